// Round 3
// baseline (548.864 us; speedup 1.0000x reference)
//
#include <hip/hip_runtime.h>
#include <hip/hip_bf16.h>
#include <cstdint>

#define NB 4
#define NQ 512
#define NM 8192
#define NH 8
#define DH 64

typedef short bf16x8s __attribute__((ext_vector_type(8)));
typedef short bf16x4s __attribute__((ext_vector_type(4)));
typedef float f32x4  __attribute__((ext_vector_type(4)));

// fast fp32->bf16 (round-half-up)
static __device__ __forceinline__ short f2bs(float f) {
    unsigned u = __builtin_bit_cast(unsigned, f);
    return (short)(unsigned short)((u + 0x8000u) >> 16);
}
// packed pair via v_perm_b32: lo16 = bf16(a), hi16 = bf16(b)
static __device__ __forceinline__ unsigned pk2(float a, float b) {
    unsigned au = __builtin_bit_cast(unsigned, a) + 0x8000u;
    unsigned bu = __builtin_bit_cast(unsigned, b) + 0x8000u;
    return __builtin_amdgcn_perm(bu, au, 0x07060302u);
}

#if __has_builtin(__builtin_amdgcn_exp2f)
static __device__ __forceinline__ float fexp2(float x) { return __builtin_amdgcn_exp2f(x); }
#else
static __device__ __forceinline__ float fexp2(float x) { return exp2f(x); }
#endif

// ---------------------------------------------------------------------------
// Weight prep: Wq/Wo [512,512], Wkv [256,1024] (fp32 [k][n]) -> bf16 MFMA
// B-fragment order: Wf[(n0*KS + ks)*64 + lane][j] = W[ks*32+quad*8+j][n0*16+m16]
// ---------------------------------------------------------------------------
__global__ __launch_bounds__(256) void prep_weights(
    const float* __restrict__ Wq, const float* __restrict__ Wo,
    const float* __restrict__ Wkv,
    short* __restrict__ Wqf, short* __restrict__ Wof, short* __restrict__ Wkvf)
{
    const int t = threadIdx.x;
    const int w = t >> 6, ln = t & 63;
    const int m16 = ln & 15, quad = ln >> 4;
    int f = blockIdx.x * 4 + w;           // 0..1535
    const float* src; short* dst; int N, KS, n0, ks;
    if (f < 512)       { src = Wq;  dst = Wqf;  N = 512;  KS = 16; n0 = f >> 4; ks = f & 15; }
    else if (f < 1024) { f -= 512;  src = Wo;  dst = Wof;  N = 512;  KS = 16; n0 = f >> 4; ks = f & 15; }
    else               { f -= 1024; src = Wkv; dst = Wkvf; N = 1024; KS = 8;  n0 = f >> 3; ks = f & 7; }
    const float* sp = src + (size_t)(ks * 32 + quad * 8) * N + n0 * 16 + m16;
    float v[8];
    #pragma unroll
    for (int j = 0; j < 8; ++j) v[j] = sp[(size_t)j * N];
    uint4 pkv = { pk2(v[0],v[1]), pk2(v[2],v[3]), pk2(v[4],v[5]), pk2(v[6],v[7]) };
    *(uint4*)(dst + ((size_t)(n0 * KS + ks) * 64 + ln) * 8) = pkv;
}

// ---------------------------------------------------------------------------
// Plain projection body (q = x @ Wq): 32x64 tile, BK=64, 256 threads (passed t).
// ---------------------------------------------------------------------------
__device__ __forceinline__ void proj32_body(
    const float* __restrict__ A, const short* __restrict__ Wf,
    float* __restrict__ C, const float* __restrict__ bias,
    int tm, int tn, char* smemraw, int t)
{
    short* As = (short*)smemraw;        // 2 x [32][72]

    const int w = t >> 6, ln = t & 63;
    const int m16 = ln & 15, quad = ln >> 4;
    const int wm = w >> 1, wn = w & 1;

    const int ar = t >> 3, ac = (t & 7) << 3;      // A: 32 rows x 64 k

    const float* Ap = A + (size_t)(tm * 32 + ar) * 512 + ac;

    f32x4 acc[2] = {};

    {
        float4 a0 = *(const float4*)(Ap);
        float4 a1 = *(const float4*)(Ap + 4);
        uint4 wa = { pk2(a0.x,a0.y), pk2(a0.z,a0.w), pk2(a1.x,a1.y), pk2(a1.z,a1.w) };
        *(uint4*)&As[ar * 72 + ac] = wa;
    }

    #pragma unroll
    for (int k0 = 0; k0 < 512; k0 += 64) {
        short* Ab = As + ((k0 >> 6) & 1) * 2304;
        __syncthreads();

        bf16x8s bfr[2][2];
        #pragma unroll
        for (int ks = 0; ks < 2; ++ks)
            #pragma unroll
            for (int nt = 0; nt < 2; ++nt)
                bfr[ks][nt] = *(const bf16x8s*)(Wf +
                    ((size_t)((tn * 4 + wn * 2 + nt) * 16 + (k0 >> 5) + ks) * 64 + ln) * 8);

        bf16x8s afr[2];
        #pragma unroll
        for (int ks = 0; ks < 2; ++ks)
            afr[ks] = *(const bf16x8s*)&Ab[(wm * 16 + m16) * 72 + ks * 32 + quad * 8];

        float4 a0n, a1n;
        if (k0 + 64 < 512) {
            a0n = *(const float4*)(Ap + k0 + 64);
            a1n = *(const float4*)(Ap + k0 + 68);
        }

        #pragma unroll
        for (int ks = 0; ks < 2; ++ks)
            #pragma unroll
            for (int nt = 0; nt < 2; ++nt)
                acc[nt] = __builtin_amdgcn_mfma_f32_16x16x32_bf16(afr[ks], bfr[ks][nt], acc[nt], 0, 0, 0);

        if (k0 + 64 < 512) {
            short* Abn = As + ((((k0 >> 6) + 1) & 1)) * 2304;
            uint4 wa = { pk2(a0n.x,a0n.y), pk2(a0n.z,a0n.w), pk2(a1n.x,a1n.y), pk2(a1n.z,a1n.w) };
            *(uint4*)&Abn[ar * 72 + ac] = wa;
        }
    }

    const int row0 = tm * 32 + wm * 16 + quad * 4;
    const int col0 = tn * 64 + wn * 32;
    #pragma unroll
    for (int nt = 0; nt < 2; ++nt) {
        const int col = col0 + nt * 16 + m16;
        const float bb = bias ? bias[col] : 0.f;
        #pragma unroll
        for (int r = 0; r < 4; ++r)
            C[(size_t)(row0 + r) * 512 + col] = acc[nt][r] + bb;
    }
}

// ---------------------------------------------------------------------------
// Out-projection body with attention-partial merge:
// A = (A0 + A1) * (1 / (l0 + l1)) per (row, head), head = k0>>6.
// ---------------------------------------------------------------------------
__device__ __forceinline__ void projo_body(
    const float* __restrict__ A0, const float* __restrict__ A1,
    const float* __restrict__ l0p, const float* __restrict__ l1p,
    const short* __restrict__ Wf,
    float* __restrict__ C, const float* __restrict__ bias,
    int tm, int tn, char* smemraw, int t)
{
    short* As = (short*)smemraw;        // 2 x [32][72]

    const int w = t >> 6, ln = t & 63;
    const int m16 = ln & 15, quad = ln >> 4;
    const int wm = w >> 1, wn = w & 1;

    const int ar = t >> 3, ac = (t & 7) << 3;

    const int row = tm * 32 + ar;                  // 0..2047
    const int lbase = ((row >> 9) * NH) * NQ + (row & 511);

    // per-head scale factors (8 heads along the k dim)
    float sc[8];
    #pragma unroll
    for (int h = 0; h < 8; ++h)
        sc[h] = 1.0f / (l0p[lbase + h * NQ] + l1p[lbase + h * NQ]);

    const float* Ap0 = A0 + (size_t)row * 512 + ac;
    const float* Ap1 = A1 + (size_t)row * 512 + ac;

    f32x4 acc[2] = {};

    {
        float4 a0 = *(const float4*)(Ap0);
        float4 b0 = *(const float4*)(Ap1);
        float4 a1 = *(const float4*)(Ap0 + 4);
        float4 b1 = *(const float4*)(Ap1 + 4);
        const float s = sc[0];
        uint4 wa = { pk2((a0.x+b0.x)*s,(a0.y+b0.y)*s), pk2((a0.z+b0.z)*s,(a0.w+b0.w)*s),
                     pk2((a1.x+b1.x)*s,(a1.y+b1.y)*s), pk2((a1.z+b1.z)*s,(a1.w+b1.w)*s) };
        *(uint4*)&As[ar * 72 + ac] = wa;
    }

    #pragma unroll
    for (int k0 = 0; k0 < 512; k0 += 64) {
        short* Ab = As + ((k0 >> 6) & 1) * 2304;
        __syncthreads();

        bf16x8s bfr[2][2];
        #pragma unroll
        for (int ks = 0; ks < 2; ++ks)
            #pragma unroll
            for (int nt = 0; nt < 2; ++nt)
                bfr[ks][nt] = *(const bf16x8s*)(Wf +
                    ((size_t)((tn * 4 + wn * 2 + nt) * 16 + (k0 >> 5) + ks) * 64 + ln) * 8);

        bf16x8s afr[2];
        #pragma unroll
        for (int ks = 0; ks < 2; ++ks)
            afr[ks] = *(const bf16x8s*)&Ab[(wm * 16 + m16) * 72 + ks * 32 + quad * 8];

        float4 a0n, b0n, a1n, b1n;
        if (k0 + 64 < 512) {
            a0n = *(const float4*)(Ap0 + k0 + 64);
            b0n = *(const float4*)(Ap1 + k0 + 64);
            a1n = *(const float4*)(Ap0 + k0 + 68);
            b1n = *(const float4*)(Ap1 + k0 + 68);
        }

        #pragma unroll
        for (int ks = 0; ks < 2; ++ks)
            #pragma unroll
            for (int nt = 0; nt < 2; ++nt)
                acc[nt] = __builtin_amdgcn_mfma_f32_16x16x32_bf16(afr[ks], bfr[ks][nt], acc[nt], 0, 0, 0);

        if (k0 + 64 < 512) {
            short* Abn = As + ((((k0 >> 6) + 1) & 1)) * 2304;
            const float s = sc[(k0 >> 6) + 1];
            uint4 wa = { pk2((a0n.x+b0n.x)*s,(a0n.y+b0n.y)*s), pk2((a0n.z+b0n.z)*s,(a0n.w+b0n.w)*s),
                         pk2((a1n.x+b1n.x)*s,(a1n.y+b1n.y)*s), pk2((a1n.z+b1n.z)*s,(a1n.w+b1n.w)*s) };
            *(uint4*)&Abn[ar * 72 + ac] = wa;
        }
    }

    const int row0 = tm * 32 + wm * 16 + quad * 4;
    const int col0 = tn * 64 + wn * 32;
    #pragma unroll
    for (int nt = 0; nt < 2; ++nt) {
        const int col = col0 + nt * 16 + m16;
        const float bb = bias[col];
        #pragma unroll
        for (int r = 0; r < 4; ++r)
            C[(size_t)(row0 + r) * 512 + col] = acc[nt][r] + bb;
    }
}

// ---------------------------------------------------------------------------
// kv GEMM body: 128x256 tile, 512 threads (8 waves: wm=w&1, wn=w>>1 in 0..3),
// BK=32, K=256. A (fp32->bf16) LDS-staged; W-fragments LDS-staged once per
// block (halves L1 weight traffic). Double-buffered, 1 barrier/step.
// K epilogue: wave-local LDS transpose -> coalesced uint4 stores.
// V epilogue: producer lane == consumer lane: direct uint4 stores.
// ---------------------------------------------------------------------------
__device__ __forceinline__ void kv_body(
    const float* __restrict__ A, const short* __restrict__ Wkvf,
    short* __restrict__ Kf, short* __restrict__ Vf,
    int kvid, char* smemraw)
{
    short* As = (short*)smemraw;                 // 2 x [128][40] shorts (20480 B)
    short* Ws = (short*)(smemraw + 20480);       // 2 x 8192 shorts (32768 B)

    const int t  = threadIdx.x;
    // XCD swizzle: 4 n-slices of one m-tile on the same XCD
    const int tm  = ((kvid >> 5) << 3) | (kvid & 7);   // 0..255
    const int tn0 = (kvid >> 3) & 3;                   // 256-col slice
    const int w  = t >> 6, ln = t & 63;
    const int m16 = ln & 15, quad = ln >> 4;
    const int wm = w & 1, wn = w >> 1;                 // wn 0..3

    const int ar  = t >> 2;            // 0..127
    const int acf = (t & 3) << 3;      // 0,8,16,24

    const float* Abase = A + (size_t)(tm * 128 + ar) * 256 + acf;
    const short* Wb = Wkvf + (size_t)tn0 * 16 * 8 * 512;

    f32x4 acc[4][4] = {};

    // prologue: stage s=0 into buffer 0
    {
        float4 a0 = *(const float4*)(Abase);
        float4 a1 = *(const float4*)(Abase + 4);
        uint4 wa = { pk2(a0.x,a0.y), pk2(a0.z,a0.w), pk2(a1.x,a1.y), pk2(a1.z,a1.w) };
        *(uint4*)&As[ar * 40 + acf] = wa;
        uint4 w0 = *(const uint4*)(Wb + ((size_t)(w * 8)) * 512 + ln * 8);
        uint4 w1 = *(const uint4*)(Wb + ((size_t)((8 + w) * 8)) * 512 + ln * 8);
        *(uint4*)&Ws[w * 512 + ln * 8] = w0;
        *(uint4*)&Ws[4096 + w * 512 + ln * 8] = w1;
    }

    #pragma unroll
    for (int s = 0; s < 8; ++s) {
        const int b = s & 1;
        short* Ab = As + b * 5120;
        short* Wc = Ws + b * 8192;
        __syncthreads();

        // prefetch globals for step s+1 (in flight across the MFMAs)
        uint4 w0n, w1n; float4 a0n, a1n;
        if (s < 7) {
            w0n = *(const uint4*)(Wb + ((size_t)(w * 8) + (s + 1)) * 512 + ln * 8);
            w1n = *(const uint4*)(Wb + ((size_t)((8 + w) * 8) + (s + 1)) * 512 + ln * 8);
            a0n = *(const float4*)(Abase + (s + 1) * 32);
            a1n = *(const float4*)(Abase + (s + 1) * 32 + 4);
        }

        bf16x8s bfr[4];
        #pragma unroll
        for (int j = 0; j < 4; ++j)
            bfr[j] = *(const bf16x8s*)&Wc[(wn * 4 + j) * 512 + ln * 8];
        bf16x8s af[4];
        #pragma unroll
        for (int i = 0; i < 4; ++i)
            af[i] = *(const bf16x8s*)&Ab[(wm * 64 + i * 16 + m16) * 40 + quad * 8];

        #pragma unroll
        for (int i = 0; i < 4; ++i)
            #pragma unroll
            for (int j = 0; j < 4; ++j)
                acc[i][j] = __builtin_amdgcn_mfma_f32_16x16x32_bf16(af[i], bfr[j], acc[i][j], 0, 0, 0);

        if (s < 7) {
            short* Abn = As + (b ^ 1) * 5120;
            short* Wcn = Ws + (b ^ 1) * 8192;
            uint4 wa = { pk2(a0n.x,a0n.y), pk2(a0n.z,a0n.w), pk2(a1n.x,a1n.y), pk2(a1n.z,a1n.w) };
            *(uint4*)&Abn[ar * 40 + acf] = wa;
            *(uint4*)&Wcn[w * 512 + ln * 8] = w0n;
            *(uint4*)&Wcn[4096 + w * 512 + ln * 8] = w1n;
        }
    }

    const int col0 = tn0 * 256 + wn * 64;
    const int row0 = tm * 128 + wm * 64;
    const int b    = row0 >> 13;
    const int mr0  = row0 & (NM - 1);

    if (col0 < 512) {
        // K epilogue (tn0 in {0,1}: whole block is K; barrier block-uniform)
        __syncthreads();
        const int h = col0 >> 6;
        short* Kp = Kf + (size_t)(b * NH + h) * (NM * DH);
        short* S  = (short*)smemraw + w * 2048;
        #pragma unroll
        for (int half = 0; half < 2; ++half) {
            const int i0 = half * 2;
            #pragma unroll
            for (int di = 0; di < 2; ++di)
                #pragma unroll
                for (int j = 0; j < 4; ++j) {
                    const int d    = j * 16 + m16;
                    const int fl   = di * 2 + (d >> 5);
                    const int base = fl * 512 + (((d >> 3) & 3) * 16 + quad * 4) * 8 + (d & 7);
                    #pragma unroll
                    for (int r = 0; r < 4; ++r)
                        S[base + r * 8] = f2bs(acc[i0 + di][j][r]);
                }
            const int gf0 = ((mr0 >> 4) + i0) * 2;
            #pragma unroll
            for (int fl = 0; fl < 4; ++fl) {
                uint4 v = *(const uint4*)&S[fl * 512 + ln * 8];
                *(uint4*)(Kp + ((size_t)(gf0 + fl) * 512 + ln * 8)) = v;
            }
        }
    } else {
        // V epilogue: producer lane == consumer lane, direct stores
        const int h = (col0 - 512) >> 6;
        short* Vp = Vf + (size_t)(b * NH + h) * (NM * DH);
        #pragma unroll
        for (int j = 0; j < 4; ++j)
            #pragma unroll
            for (int p = 0; p < 2; ++p) {
                uint4 v;
                v.x = pk2(acc[2*p    ][j][0], acc[2*p    ][j][1]);
                v.y = pk2(acc[2*p    ][j][2], acc[2*p    ][j][3]);
                v.z = pk2(acc[2*p + 1][j][0], acc[2*p + 1][j][1]);
                v.w = pk2(acc[2*p + 1][j][2], acc[2*p + 1][j][3]);
                *(uint4*)(Vp + ((size_t)(j * 256 + (mr0 >> 5) + p) * 64 + ln) * 8) = v;
            }
    }
}

// ---------------------------------------------------------------------------
// Uber kernel, 512 threads: blocks 0..255 = q-proj (2 x 32x64 units),
// blocks 256..1279 = kv (128x256 tiles).
// ---------------------------------------------------------------------------
__global__ __launch_bounds__(512, 4) void gemm_kvq(
    const float* __restrict__ x,   const short* __restrict__ Wqf, float* __restrict__ q,
    const float* __restrict__ ctx, const short* __restrict__ Wkvf,
    short* __restrict__ Kf, short* __restrict__ Vf)
{
    __shared__ __align__(16) char smem[53248];
    if (blockIdx.x < 256) {
        const int u = (int)(blockIdx.x * 2) + (int)(threadIdx.x >> 8);
        proj32_body(x, Wqf, q, nullptr, u >> 3, u & 7,
                    smem + (threadIdx.x >> 8) * 9216, (int)(threadIdx.x & 255));
    } else {
        kv_body(ctx, Wkvf, Kf, Vf, (int)(blockIdx.x - 256), smem);
    }
}

// out-projection with partial merge: 512 blocks x 256 threads
__global__ __launch_bounds__(256) void gemm_proj32(
    const float* __restrict__ A0, const float* __restrict__ A1,
    const float* __restrict__ l0, const float* __restrict__ l1,
    const short* __restrict__ Wf,
    float* __restrict__ C, const float* __restrict__ bias)
{
    __shared__ __align__(16) char smem[32 * 72 * 2 * 2];
    projo_body(A0, A1, l0, l1, Wf, C, bias,
               (int)(blockIdx.x >> 3), (int)(blockIdx.x & 7), smem, (int)threadIdx.x);
}

// ---------------------------------------------------------------------------
// MFMA flash attention, 64-row q-tiles x half-key-range, 8 waves (512 thr).
// 512 blocks = (bh, qt 0..7, kh 0..1): 2 blocks/CU, 4 waves/SIMD.
// Each block does 4096 keys (8 its) and writes UNNORMALIZED O-partial + l.
// The out-projection merges (o0+o1)/(l0+l1).
// S^T via 16x16x32 (B = Q frag). PV via 16x16x16 with P^T direct feed.
// ---------------------------------------------------------------------------
__global__ __launch_bounds__(512, 4) void attn_mfma(
    const float* __restrict__ Q,    // [2048, 512] fp32
    const short* __restrict__ Kfr,  // fragment-order K (16x16x32 B-op)
    const short* __restrict__ Vfr,  // fragment-order V (16x16x16 A-op)
    float* __restrict__ Op,         // 2 x [2048, 512] fp32 (kh partials)
    float* __restrict__ Lp)         // 2 x [32, 512] fp32 (kh l-partials)
{
    __shared__ __align__(16) float Ob[2][64 * 66];   // 33.8 KB
    __shared__ float lbuf[8 * 64];

    const int bid = blockIdx.x;
    const int xcd = bid & 7, g = bid >> 3;
    const int bh  = xcd * 4 + (g & 3);     // = b*8 + h, 0..31
    const int qt  = (g >> 2) & 7;          // 64-row tile
    const int kh  = g >> 5;                // key half
    const int b   = bh >> 3, h = bh & 7;
    const int t   = threadIdx.x;
    const int w   = t >> 6, ln = t & 63;
    const int m16 = ln & 15, quad = ln >> 4;

    const short* Kbase = Kfr + (size_t)bh * (NM * DH);
    const short* Vbase = Vfr + (size_t)bh * (NM * DH);
    const int it0 = kh * 8;

    // Q scaled by (1/8) * log2(e)  -> scores in log2 domain
    const float qsc = 0.125f * 1.44269504f;
    bf16x8s qf[4][2];
    #pragma unroll
    for (int mt = 0; mt < 4; ++mt) {
        const float* qrow = Q + ((size_t)(b * NQ + qt * 64 + mt * 16 + m16)) * 512 + h * 64;
        #pragma unroll
        for (int ks = 0; ks < 2; ++ks) {
            float4 x0 = *(const float4*)(qrow + ks * 32 + quad * 8);
            float4 x1 = *(const float4*)(qrow + ks * 32 + quad * 8 + 4);
            uint4 pkv = { pk2(x0.x * qsc, x0.y * qsc), pk2(x0.z * qsc, x0.w * qsc),
                          pk2(x1.x * qsc, x1.y * qsc), pk2(x1.z * qsc, x1.w * qsc) };
            qf[mt][ks] = *reinterpret_cast<bf16x8s*>(&pkv);
        }
    }

    bf16x4s ones4;
    #pragma unroll
    for (int j = 0; j < 4; ++j) ones4[j] = (short)0x3F80;

    f32x4 o[4][4] = {};
    f32x4 lsum[4] = {};

    bf16x8s kf[4][2];
    {
        const int kc = it0 * 512 + w * 64;
        #pragma unroll
        for (int nt = 0; nt < 4; ++nt)
            #pragma unroll
            for (int ks = 0; ks < 2; ++ks)
                kf[nt][ks] = *(const bf16x8s*)(Kbase + ((((kc >> 4) + nt) * 2 + ks) << 9) + ln * 8);
    }

    for (int it = it0; it < it0 + 8; ++it) {
        const int kc = it * 512 + w * 64;

        // V frags: b128 per (dt, ktpair); halves are K=16 A-operands
        uint4 vraw[4][2];
        #pragma unroll
        for (int dt = 0; dt < 4; ++dt)
            #pragma unroll
            for (int kp = 0; kp < 2; ++kp)
                vraw[dt][kp] = *(const uint4*)(Vbase + ((size_t)(dt * 256 + (kc >> 5) + kp) * 64 + ln) * 8);

        // S^T : 16x16x32, C-layout key=quad*4+r (within kt tile), q=m16
        f32x4 st[4][4] = {};
        __builtin_amdgcn_s_setprio(1);
        #pragma unroll
        for (int kt = 0; kt < 4; ++kt)
            #pragma unroll
            for (int mt = 0; mt < 4; ++mt) {
                st[mt][kt] = __builtin_amdgcn_mfma_f32_16x16x32_bf16(kf[kt][0], qf[mt][0], st[mt][kt], 0, 0, 0);
                st[mt][kt] = __builtin_amdgcn_mfma_f32_16x16x32_bf16(kf[kt][1], qf[mt][1], st[mt][kt], 0, 0, 0);
            }
        __builtin_amdgcn_s_setprio(0);

        if (it + 1 < it0 + 8) {
            const int kn = (it + 1) * 512 + w * 64;
            #pragma unroll
            for (int nt = 0; nt < 4; ++nt)
                #pragma unroll
                for (int ks = 0; ks < 2; ++ks)
                    kf[nt][ks] = *(const bf16x8s*)(Kbase + ((((kn >> 4) + nt) * 2 + ks) << 9) + ln * 8);
        }

        // p = 2^s, pack -> K=16 B-operand directly (no cross-lane ops!)
        #pragma unroll
        for (int mt = 0; mt < 4; ++mt)
            #pragma unroll
            for (int kt = 0; kt < 4; ++kt) {
                const float p0 = fexp2(st[mt][kt][0]);
                const float p1 = fexp2(st[mt][kt][1]);
                const float p2 = fexp2(st[mt][kt][2]);
                const float p3 = fexp2(st[mt][kt][3]);
                uint2 pu = { pk2(p0, p1), pk2(p2, p3) };
                bf16x4s pbv = *reinterpret_cast<bf16x4s*>(&pu);
                const int kp = kt >> 1, hh = kt & 1;
                __builtin_amdgcn_s_setprio(1);
                #pragma unroll
                for (int dt = 0; dt < 4; ++dt) {
                    uint2 vh = hh ? make_uint2(vraw[dt][kp].z, vraw[dt][kp].w)
                                  : make_uint2(vraw[dt][kp].x, vraw[dt][kp].y);
                    bf16x4s va = *reinterpret_cast<bf16x4s*>(&vh);
                    o[mt][dt] = __builtin_amdgcn_mfma_f32_16x16x16bf16_1k(va, pbv, o[mt][dt], 0, 0, 0);
                }
                lsum[mt] = __builtin_amdgcn_mfma_f32_16x16x16bf16_1k(ones4, pbv, lsum[mt], 0, 0, 0);
                __builtin_amdgcn_s_setprio(0);
            }
    }

    // ---- epilogue: l partials + 8-wave 2-buffer O merge (unnormalized) ----
    if (quad == 0) {
        #pragma unroll
        for (int mt = 0; mt < 4; ++mt)
            lbuf[w * 64 + mt * 16 + m16] = lsum[mt][0];
    }
    if (w < 2) {
        float* dst = Ob[w];
        #pragma unroll
        for (int mt = 0; mt < 4; ++mt)
            #pragma unroll
            for (int dt = 0; dt < 4; ++dt)
                *(f32x4*)&dst[(mt * 16 + m16) * 66 + dt * 16 + quad * 4] = o[mt][dt];
    }
    __syncthreads();
    #pragma unroll
    for (int ph = 1; ph < 4; ++ph) {
        if ((w >> 1) == ph) {
            float* dst = Ob[w & 1];
            #pragma unroll
            for (int mt = 0; mt < 4; ++mt)
                #pragma unroll
                for (int dt = 0; dt < 4; ++dt) {
                    float* p = &dst[(mt * 16 + m16) * 66 + dt * 16 + quad * 4];
                    f32x4 cur = *(f32x4*)p;
                    cur += o[mt][dt];
                    *(f32x4*)p = cur;
                }
        }
        __syncthreads();
    }
    // Final: combine the two buffers, store unnormalized; store l partials
    {
        float* Og = Op + (size_t)kh * (2048 * 512);
        const int row = t >> 3;             // 0..63
        const int d0  = (t & 7) << 3;       // 8 floats per thread
        float* op = Og + ((size_t)(b * NQ + qt * 64 + row)) * 512 + h * 64 + d0;
        #pragma unroll
        for (int j = 0; j < 2; ++j) {
            const int c = row * 66 + d0 + j * 4;
            float4 r;
            r.x = Ob[0][c + 0] + Ob[1][c + 0];
            r.y = Ob[0][c + 1] + Ob[1][c + 1];
            r.z = Ob[0][c + 2] + Ob[1][c + 2];
            r.w = Ob[0][c + 3] + Ob[1][c + 3];
            *(float4*)(op + j * 4) = r;
        }
        if (t < 64) {
            float l = 0.f;
            #pragma unroll
            for (int wi = 0; wi < 8; ++wi) l += lbuf[wi * 64 + t];
            Lp[(size_t)kh * (32 * NQ) + bh * NQ + qt * 64 + t] = l;
        }
    }
}

// ---------------------------------------------------------------------------
extern "C" void kernel_launch(void* const* d_in, const int* in_sizes, int n_in,
                              void* d_out, int out_size, void* d_ws, size_t ws_size,
                              hipStream_t stream) {
    (void)in_sizes; (void)n_in; (void)out_size; (void)ws_size;

    const float* x   = (const float*)d_in[0];   // [4, 512, 512]
    const float* ctx = (const float*)d_in[1];   // [4, 8192, 256]
    const float* Wq  = (const float*)d_in[2];   // [512, 512]
    const float* Wkv = (const float*)d_in[3];   // [256, 1024]
    const float* Wo  = (const float*)d_in[4];   // [512, 512]
    const float* bo  = (const float*)d_in[5];   // [512]
    float* out = (float*)d_out;                 // [4, 512, 512]

    float* ws    = (float*)d_ws;
    float* q     = ws;                                       // 4 MB fp32
    float* attno = q + (size_t)2048 * 512;                   // 2 x 4 MB fp32 (kh partials)
    float* lws   = attno + (size_t)2 * 2048 * 512;           // 2 x 64 KB fp32
    short* Kf    = (short*)(lws + (size_t)2 * 32 * NQ);      // 33.5 MB bf16 (fragment order)
    short* Vf    = Kf + (size_t)NB * NH * NM * DH;           // 33.5 MB bf16 (fragment order)
    short* Wqf   = Vf + (size_t)NB * NH * NM * DH;           // 512 KB
    short* Wof   = Wqf + (size_t)512 * 512;                  // 512 KB
    short* Wkvf  = Wof + (size_t)512 * 512;                  // 512 KB

    // weights -> bf16 fragment order
    prep_weights<<<dim3(384), dim3(256), 0, stream>>>(Wq, Wo, Wkv, Wqf, Wof, Wkvf);

    // q = x@Wq (256 blocks x 2 units) + kv = ctx@Wkv (1024 blocks), 512 thr
    gemm_kvq<<<dim3(1280), dim3(512), 0, stream>>>(x, Wqf, q, ctx, Wkvf, Kf, Vf);

    // flash attention: 32 bh x 8 q-tiles x 2 key-halves = 512 blocks x 512 thr
    attn_mfma<<<dim3(512), dim3(512), 0, stream>>>(q, Kf, Vf, attno, lws);

    // out = merge(attno halves) @ Wo + bo (512 blocks)
    gemm_proj32<<<dim3(512), dim3(256), 0, stream>>>(
        attno, attno + (size_t)2048 * 512, lws, lws + (size_t)32 * NQ,
        Wof, out, bo);
}

// Round 4
// 191.136 us; speedup vs baseline: 2.8716x; 2.8716x over previous
//
#include <hip/hip_runtime.h>
#include <hip/hip_bf16.h>
#include <cstdint>

#define NB 4
#define NQ 512
#define NM 8192
#define NH 8
#define DH 64

typedef short bf16x8s __attribute__((ext_vector_type(8)));
typedef short bf16x4s __attribute__((ext_vector_type(4)));
typedef float f32x4  __attribute__((ext_vector_type(4)));

// fast fp32->bf16 (round-half-up)
static __device__ __forceinline__ short f2bs(float f) {
    unsigned u = __builtin_bit_cast(unsigned, f);
    return (short)(unsigned short)((u + 0x8000u) >> 16);
}
// packed pair via v_perm_b32: lo16 = bf16(a), hi16 = bf16(b)
static __device__ __forceinline__ unsigned pk2(float a, float b) {
    unsigned au = __builtin_bit_cast(unsigned, a) + 0x8000u;
    unsigned bu = __builtin_bit_cast(unsigned, b) + 0x8000u;
    return __builtin_amdgcn_perm(bu, au, 0x07060302u);
}

#if __has_builtin(__builtin_amdgcn_exp2f)
static __device__ __forceinline__ float fexp2(float x) { return __builtin_amdgcn_exp2f(x); }
#else
static __device__ __forceinline__ float fexp2(float x) { return exp2f(x); }
#endif

// ---------------------------------------------------------------------------
// Weight prep: Wq/Wo [512,512], Wkv [256,1024] (fp32 [k][n]) -> bf16 MFMA
// B-fragment order: Wf[(n0*KS + ks)*64 + lane][j] = W[ks*32+quad*8+j][n0*16+m16]
// ---------------------------------------------------------------------------
__global__ __launch_bounds__(256) void prep_weights(
    const float* __restrict__ Wq, const float* __restrict__ Wo,
    const float* __restrict__ Wkv,
    short* __restrict__ Wqf, short* __restrict__ Wof, short* __restrict__ Wkvf)
{
    const int t = threadIdx.x;
    const int w = t >> 6, ln = t & 63;
    const int m16 = ln & 15, quad = ln >> 4;
    int f = blockIdx.x * 4 + w;           // 0..1535
    const float* src; short* dst; int N, KS, n0, ks;
    if (f < 512)       { src = Wq;  dst = Wqf;  N = 512;  KS = 16; n0 = f >> 4; ks = f & 15; }
    else if (f < 1024) { f -= 512;  src = Wo;  dst = Wof;  N = 512;  KS = 16; n0 = f >> 4; ks = f & 15; }
    else               { f -= 1024; src = Wkv; dst = Wkvf; N = 1024; KS = 8;  n0 = f >> 3; ks = f & 7; }
    const float* sp = src + (size_t)(ks * 32 + quad * 8) * N + n0 * 16 + m16;
    float v[8];
    #pragma unroll
    for (int j = 0; j < 8; ++j) v[j] = sp[(size_t)j * N];
    uint4 pkv = { pk2(v[0],v[1]), pk2(v[2],v[3]), pk2(v[4],v[5]), pk2(v[6],v[7]) };
    *(uint4*)(dst + ((size_t)(n0 * KS + ks) * 64 + ln) * 8) = pkv;
}

// ---------------------------------------------------------------------------
// Plain projection body (q = x @ Wq): 32x64 tile, BK=64, 256 threads (passed t).
// ---------------------------------------------------------------------------
__device__ __forceinline__ void proj32_body(
    const float* __restrict__ A, const short* __restrict__ Wf,
    float* __restrict__ C, const float* __restrict__ bias,
    int tm, int tn, char* smemraw, int t)
{
    short* As = (short*)smemraw;        // 2 x [32][72]

    const int w = t >> 6, ln = t & 63;
    const int m16 = ln & 15, quad = ln >> 4;
    const int wm = w >> 1, wn = w & 1;

    const int ar = t >> 3, ac = (t & 7) << 3;      // A: 32 rows x 64 k

    const float* Ap = A + (size_t)(tm * 32 + ar) * 512 + ac;

    f32x4 acc[2] = {};

    {
        float4 a0 = *(const float4*)(Ap);
        float4 a1 = *(const float4*)(Ap + 4);
        uint4 wa = { pk2(a0.x,a0.y), pk2(a0.z,a0.w), pk2(a1.x,a1.y), pk2(a1.z,a1.w) };
        *(uint4*)&As[ar * 72 + ac] = wa;
    }

    #pragma unroll
    for (int k0 = 0; k0 < 512; k0 += 64) {
        short* Ab = As + ((k0 >> 6) & 1) * 2304;
        __syncthreads();

        bf16x8s bfr[2][2];
        #pragma unroll
        for (int ks = 0; ks < 2; ++ks)
            #pragma unroll
            for (int nt = 0; nt < 2; ++nt)
                bfr[ks][nt] = *(const bf16x8s*)(Wf +
                    ((size_t)((tn * 4 + wn * 2 + nt) * 16 + (k0 >> 5) + ks) * 64 + ln) * 8);

        bf16x8s afr[2];
        #pragma unroll
        for (int ks = 0; ks < 2; ++ks)
            afr[ks] = *(const bf16x8s*)&Ab[(wm * 16 + m16) * 72 + ks * 32 + quad * 8];

        float4 a0n, a1n;
        if (k0 + 64 < 512) {
            a0n = *(const float4*)(Ap + k0 + 64);
            a1n = *(const float4*)(Ap + k0 + 68);
        }

        #pragma unroll
        for (int ks = 0; ks < 2; ++ks)
            #pragma unroll
            for (int nt = 0; nt < 2; ++nt)
                acc[nt] = __builtin_amdgcn_mfma_f32_16x16x32_bf16(afr[ks], bfr[ks][nt], acc[nt], 0, 0, 0);

        if (k0 + 64 < 512) {
            short* Abn = As + ((((k0 >> 6) + 1) & 1)) * 2304;
            uint4 wa = { pk2(a0n.x,a0n.y), pk2(a0n.z,a0n.w), pk2(a1n.x,a1n.y), pk2(a1n.z,a1n.w) };
            *(uint4*)&Abn[ar * 72 + ac] = wa;
        }
    }

    const int row0 = tm * 32 + wm * 16 + quad * 4;
    const int col0 = tn * 64 + wn * 32;
    #pragma unroll
    for (int nt = 0; nt < 2; ++nt) {
        const int col = col0 + nt * 16 + m16;
        const float bb = bias ? bias[col] : 0.f;
        #pragma unroll
        for (int r = 0; r < 4; ++r)
            C[(size_t)(row0 + r) * 512 + col] = acc[nt][r] + bb;
    }
}

// ---------------------------------------------------------------------------
// Out-projection body with attention-partial merge:
// A = (A0 + A1) * (1 / (l0 + l1)) per (row, head), head = k0>>6.
// ---------------------------------------------------------------------------
__device__ __forceinline__ void projo_body(
    const float* __restrict__ A0, const float* __restrict__ A1,
    const float* __restrict__ l0p, const float* __restrict__ l1p,
    const short* __restrict__ Wf,
    float* __restrict__ C, const float* __restrict__ bias,
    int tm, int tn, char* smemraw, int t)
{
    short* As = (short*)smemraw;        // 2 x [32][72]

    const int w = t >> 6, ln = t & 63;
    const int m16 = ln & 15, quad = ln >> 4;
    const int wm = w >> 1, wn = w & 1;

    const int ar = t >> 3, ac = (t & 7) << 3;

    const int row = tm * 32 + ar;                  // 0..2047
    const int lbase = ((row >> 9) * NH) * NQ + (row & 511);

    // per-head scale factors (8 heads along the k dim)
    float sc[8];
    #pragma unroll
    for (int h = 0; h < 8; ++h)
        sc[h] = 1.0f / (l0p[lbase + h * NQ] + l1p[lbase + h * NQ]);

    const float* Ap0 = A0 + (size_t)row * 512 + ac;
    const float* Ap1 = A1 + (size_t)row * 512 + ac;

    f32x4 acc[2] = {};

    {
        float4 a0 = *(const float4*)(Ap0);
        float4 b0 = *(const float4*)(Ap1);
        float4 a1 = *(const float4*)(Ap0 + 4);
        float4 b1 = *(const float4*)(Ap1 + 4);
        const float s = sc[0];
        uint4 wa = { pk2((a0.x+b0.x)*s,(a0.y+b0.y)*s), pk2((a0.z+b0.z)*s,(a0.w+b0.w)*s),
                     pk2((a1.x+b1.x)*s,(a1.y+b1.y)*s), pk2((a1.z+b1.z)*s,(a1.w+b1.w)*s) };
        *(uint4*)&As[ar * 72 + ac] = wa;
    }

    #pragma unroll
    for (int k0 = 0; k0 < 512; k0 += 64) {
        short* Ab = As + ((k0 >> 6) & 1) * 2304;
        __syncthreads();

        bf16x8s bfr[2][2];
        #pragma unroll
        for (int ks = 0; ks < 2; ++ks)
            #pragma unroll
            for (int nt = 0; nt < 2; ++nt)
                bfr[ks][nt] = *(const bf16x8s*)(Wf +
                    ((size_t)((tn * 4 + wn * 2 + nt) * 16 + (k0 >> 5) + ks) * 64 + ln) * 8);

        bf16x8s afr[2];
        #pragma unroll
        for (int ks = 0; ks < 2; ++ks)
            afr[ks] = *(const bf16x8s*)&Ab[(wm * 16 + m16) * 72 + ks * 32 + quad * 8];

        float4 a0n, b0n, a1n, b1n;
        if (k0 + 64 < 512) {
            a0n = *(const float4*)(Ap0 + k0 + 64);
            b0n = *(const float4*)(Ap1 + k0 + 64);
            a1n = *(const float4*)(Ap0 + k0 + 68);
            b1n = *(const float4*)(Ap1 + k0 + 68);
        }

        #pragma unroll
        for (int ks = 0; ks < 2; ++ks)
            #pragma unroll
            for (int nt = 0; nt < 2; ++nt)
                acc[nt] = __builtin_amdgcn_mfma_f32_16x16x32_bf16(afr[ks], bfr[ks][nt], acc[nt], 0, 0, 0);

        if (k0 + 64 < 512) {
            short* Abn = As + ((((k0 >> 6) + 1) & 1)) * 2304;
            const float s = sc[(k0 >> 6) + 1];
            uint4 wa = { pk2((a0n.x+b0n.x)*s,(a0n.y+b0n.y)*s), pk2((a0n.z+b0n.z)*s,(a0n.w+b0n.w)*s),
                         pk2((a1n.x+b1n.x)*s,(a1n.y+b1n.y)*s), pk2((a1n.z+b1n.z)*s,(a1n.w+b1n.w)*s) };
            *(uint4*)&Abn[ar * 72 + ac] = wa;
        }
    }

    const int row0 = tm * 32 + wm * 16 + quad * 4;
    const int col0 = tn * 64 + wn * 32;
    #pragma unroll
    for (int nt = 0; nt < 2; ++nt) {
        const int col = col0 + nt * 16 + m16;
        const float bb = bias[col];
        #pragma unroll
        for (int r = 0; r < 4; ++r)
            C[(size_t)(row0 + r) * 512 + col] = acc[nt][r] + bb;
    }
}

// ---------------------------------------------------------------------------
// kv GEMM body (known-good round-2 version): 128x128 tile, BK=32, K=256,
// 256 threads. A via double-buffered LDS with register prefetch; B-frags
// direct from frag-order Wkv.
// K epilogue: wave-local LDS transpose -> coalesced uint4 stores.
// V epilogue: producer lane == consumer lane: direct uint4 stores.
// ---------------------------------------------------------------------------
__device__ __forceinline__ void kv_body(
    const float* __restrict__ A, const short* __restrict__ Wkvf,
    short* __restrict__ Kf, short* __restrict__ Vf,
    int kvid, char* smemraw)
{
    short* As = (short*)smemraw;        // 2 x [128][40]

    const int t  = threadIdx.x;
    // temporal+XCD swizzle: 8 n-tiles of one m-tile are 8 consecutive slots
    // on the same XCD
    const int tm = ((kvid >> 6) << 3) | (kvid & 7);
    const int tn = (kvid >> 3) & 7;
    const int w  = t >> 6, ln = t & 63;
    const int m16 = ln & 15, quad = ln >> 4;
    const int wm = w & 1, wn = w >> 1;

    const int ar = t >> 3;
    const int ac = (t & 7) << 2;

    const float* Abase = A + (size_t)(tm * 128 + ar) * 256 + ac;

    f32x4 acc[4][4] = {};

    // prologue: stage k0=0 into buffer 0
    {
        float4 av[4];
        #pragma unroll
        for (int p = 0; p < 4; ++p)
            av[p] = *(const float4*)(Abase + (size_t)p * 32 * 256);
        #pragma unroll
        for (int p = 0; p < 4; ++p) {
            uint2 wv = { pk2(av[p].x, av[p].y), pk2(av[p].z, av[p].w) };
            *(uint2*)&As[(p * 32 + ar) * 40 + ac] = wv;
        }
    }

    #pragma unroll
    for (int k0 = 0; k0 < 256; k0 += 32) {
        short* Ab = As + ((k0 >> 5) & 1) * 5120;
        __syncthreads();

        bf16x8s bfr[4];
        #pragma unroll
        for (int j = 0; j < 4; ++j)
            bfr[j] = *(const bf16x8s*)(Wkvf +
                ((size_t)((tn * 8 + wn * 4 + j) * 8 + (k0 >> 5)) * 64 + ln) * 8);

        bf16x8s af[4];
        #pragma unroll
        for (int i = 0; i < 4; ++i)
            af[i] = *(const bf16x8s*)&Ab[(wm * 64 + i * 16 + m16) * 40 + quad * 8];

        // prefetch next K-step's A tile into registers
        float4 avn[4];
        if (k0 + 32 < 256) {
            #pragma unroll
            for (int p = 0; p < 4; ++p)
                avn[p] = *(const float4*)(Abase + (size_t)p * 32 * 256 + k0 + 32);
        }

        #pragma unroll
        for (int i = 0; i < 4; ++i)
            #pragma unroll
            for (int j = 0; j < 4; ++j)
                acc[i][j] = __builtin_amdgcn_mfma_f32_16x16x32_bf16(af[i], bfr[j], acc[i][j], 0, 0, 0);

        if (k0 + 32 < 256) {
            short* Abn = As + (((k0 >> 5) + 1) & 1) * 5120;
            #pragma unroll
            for (int p = 0; p < 4; ++p) {
                uint2 wv = { pk2(avn[p].x, avn[p].y), pk2(avn[p].z, avn[p].w) };
                *(uint2*)&Abn[(p * 32 + ar) * 40 + ac] = wv;
            }
        }
    }

    const int col0 = tn * 128 + wn * 64;
    const int row0 = tm * 128 + wm * 64;
    const int b    = row0 >> 13;
    const int mr0  = row0 & (NM - 1);

    if (col0 < 512) {
        // K epilogue: wave-local LDS transpose (tn<4 -> whole block is K;
        // barrier is block-uniform).
        __syncthreads();
        const int h = col0 >> 6;
        short* Kp = Kf + (size_t)(b * NH + h) * (NM * DH);
        short* S  = (short*)smemraw + w * 2048;
        #pragma unroll
        for (int half = 0; half < 2; ++half) {
            const int i0 = half * 2;
            #pragma unroll
            for (int di = 0; di < 2; ++di)
                #pragma unroll
                for (int j = 0; j < 4; ++j) {
                    const int d    = j * 16 + m16;
                    const int fl   = di * 2 + (d >> 5);
                    const int base = fl * 512 + (((d >> 3) & 3) * 16 + quad * 4) * 8 + (d & 7);
                    #pragma unroll
                    for (int r = 0; r < 4; ++r)
                        S[base + r * 8] = f2bs(acc[i0 + di][j][r]);
                }
            const int gf0 = ((mr0 >> 4) + i0) * 2;
            #pragma unroll
            for (int fl = 0; fl < 4; ++fl) {
                uint4 v = *(const uint4*)&S[fl * 512 + ln * 8];
                *(uint4*)(Kp + ((size_t)(gf0 + fl) * 512 + ln * 8)) = v;
            }
        }
    } else {
        // V: producer lane == consumer lane: direct uint4 stores
        const int h = (col0 - 512) >> 6;
        short* Vp = Vf + (size_t)(b * NH + h) * (NM * DH);
        #pragma unroll
        for (int j = 0; j < 4; ++j)
            #pragma unroll
            for (int p = 0; p < 2; ++p) {
                uint4 v;
                v.x = pk2(acc[2*p    ][j][0], acc[2*p    ][j][1]);
                v.y = pk2(acc[2*p    ][j][2], acc[2*p    ][j][3]);
                v.z = pk2(acc[2*p + 1][j][0], acc[2*p + 1][j][1]);
                v.w = pk2(acc[2*p + 1][j][2], acc[2*p + 1][j][3]);
                *(uint4*)(Vp + ((size_t)(j * 256 + (mr0 >> 5) + p) * 64 + ln) * 8) = v;
            }
    }
}

// ---------------------------------------------------------------------------
// Uber kernel: blocks 0..511 do q = x@Wq (proj32), blocks 512..2559 do kv.
// ---------------------------------------------------------------------------
__global__ __launch_bounds__(256) void gemm_kvq(
    const float* __restrict__ x,   const short* __restrict__ Wqf, float* __restrict__ q,
    const float* __restrict__ ctx, const short* __restrict__ Wkvf,
    short* __restrict__ Kf, short* __restrict__ Vf)
{
    __shared__ __align__(16) char smem[20480];
    if (blockIdx.x < 512)
        proj32_body(x, Wqf, q, nullptr, (int)(blockIdx.x >> 3), (int)(blockIdx.x & 7),
                    smem, (int)threadIdx.x);
    else
        kv_body(ctx, Wkvf, Kf, Vf, (int)(blockIdx.x - 512), smem);
}

// out-projection with partial merge: 512 blocks x 256 threads
__global__ __launch_bounds__(256) void gemm_proj32(
    const float* __restrict__ A0, const float* __restrict__ A1,
    const float* __restrict__ l0, const float* __restrict__ l1,
    const short* __restrict__ Wf,
    float* __restrict__ C, const float* __restrict__ bias)
{
    __shared__ __align__(16) char smem[32 * 72 * 2 * 2];
    projo_body(A0, A1, l0, l1, Wf, C, bias,
               (int)(blockIdx.x >> 3), (int)(blockIdx.x & 7), smem, (int)threadIdx.x);
}

// ---------------------------------------------------------------------------
// MFMA flash attention, 64-row q-tiles x half-key-range, 8 waves (512 thr).
// 512 blocks = (bh, qt 0..7, kh 0..1): 2 blocks/CU at <=128 VGPR.
// NOTE: __launch_bounds__(512, 2) -> VGPR cap 128 (measured: arg2=4 caps at
// 64 and spills catastrophically; rounds 0/1 compiled this register pattern
// to exactly 128 with arg2=2).
// Each block does 4096 keys (8 its) and writes UNNORMALIZED O-partial + l.
// The out-projection merges (o0+o1)/(l0+l1).
// S^T via 16x16x32 (B = Q frag). PV via 16x16x16 with P^T direct feed.
// ---------------------------------------------------------------------------
__global__ __launch_bounds__(512, 2) void attn_mfma(
    const float* __restrict__ Q,    // [2048, 512] fp32
    const short* __restrict__ Kfr,  // fragment-order K (16x16x32 B-op)
    const short* __restrict__ Vfr,  // fragment-order V (16x16x16 A-op)
    float* __restrict__ Op,         // 2 x [2048, 512] fp32 (kh partials)
    float* __restrict__ Lp)         // 2 x [32, 512] fp32 (kh l-partials)
{
    __shared__ __align__(16) float Ob[2][64 * 66];   // 33.8 KB
    __shared__ float lbuf[8 * 64];

    const int bid = blockIdx.x;
    const int xcd = bid & 7, g = bid >> 3;
    const int bh  = xcd * 4 + (g & 3);     // = b*8 + h, 0..31
    const int qt  = (g >> 2) & 7;          // 64-row tile
    const int kh  = g >> 5;                // key half
    const int b   = bh >> 3, h = bh & 7;
    const int t   = threadIdx.x;
    const int w   = t >> 6, ln = t & 63;
    const int m16 = ln & 15, quad = ln >> 4;

    const short* Kbase = Kfr + (size_t)bh * (NM * DH);
    const short* Vbase = Vfr + (size_t)bh * (NM * DH);
    const int it0 = kh * 8;

    // Q scaled by (1/8) * log2(e)  -> scores in log2 domain
    const float qsc = 0.125f * 1.44269504f;
    bf16x8s qf[4][2];
    #pragma unroll
    for (int mt = 0; mt < 4; ++mt) {
        const float* qrow = Q + ((size_t)(b * NQ + qt * 64 + mt * 16 + m16)) * 512 + h * 64;
        #pragma unroll
        for (int ks = 0; ks < 2; ++ks) {
            float4 x0 = *(const float4*)(qrow + ks * 32 + quad * 8);
            float4 x1 = *(const float4*)(qrow + ks * 32 + quad * 8 + 4);
            uint4 pkv = { pk2(x0.x * qsc, x0.y * qsc), pk2(x0.z * qsc, x0.w * qsc),
                          pk2(x1.x * qsc, x1.y * qsc), pk2(x1.z * qsc, x1.w * qsc) };
            qf[mt][ks] = *reinterpret_cast<bf16x8s*>(&pkv);
        }
    }

    bf16x4s ones4;
    #pragma unroll
    for (int j = 0; j < 4; ++j) ones4[j] = (short)0x3F80;

    f32x4 o[4][4] = {};
    f32x4 lsum[4] = {};

    bf16x8s kf[4][2];
    {
        const int kc = it0 * 512 + w * 64;
        #pragma unroll
        for (int nt = 0; nt < 4; ++nt)
            #pragma unroll
            for (int ks = 0; ks < 2; ++ks)
                kf[nt][ks] = *(const bf16x8s*)(Kbase + ((((kc >> 4) + nt) * 2 + ks) << 9) + ln * 8);
    }

    for (int it = it0; it < it0 + 8; ++it) {
        const int kc = it * 512 + w * 64;

        // V frags: b128 per (dt, ktpair); halves are K=16 A-operands
        uint4 vraw[4][2];
        #pragma unroll
        for (int dt = 0; dt < 4; ++dt)
            #pragma unroll
            for (int kp = 0; kp < 2; ++kp)
                vraw[dt][kp] = *(const uint4*)(Vbase + ((size_t)(dt * 256 + (kc >> 5) + kp) * 64 + ln) * 8);

        // S^T : 16x16x32, C-layout key=quad*4+r (within kt tile), q=m16
        f32x4 st[4][4] = {};
        #pragma unroll
        for (int kt = 0; kt < 4; ++kt)
            #pragma unroll
            for (int mt = 0; mt < 4; ++mt) {
                st[mt][kt] = __builtin_amdgcn_mfma_f32_16x16x32_bf16(kf[kt][0], qf[mt][0], st[mt][kt], 0, 0, 0);
                st[mt][kt] = __builtin_amdgcn_mfma_f32_16x16x32_bf16(kf[kt][1], qf[mt][1], st[mt][kt], 0, 0, 0);
            }

        if (it + 1 < it0 + 8) {
            const int kn = (it + 1) * 512 + w * 64;
            #pragma unroll
            for (int nt = 0; nt < 4; ++nt)
                #pragma unroll
                for (int ks = 0; ks < 2; ++ks)
                    kf[nt][ks] = *(const bf16x8s*)(Kbase + ((((kn >> 4) + nt) * 2 + ks) << 9) + ln * 8);
        }

        // p = 2^s, pack -> K=16 B-operand directly (no cross-lane ops!)
        #pragma unroll
        for (int mt = 0; mt < 4; ++mt)
            #pragma unroll
            for (int kt = 0; kt < 4; ++kt) {
                const float p0 = fexp2(st[mt][kt][0]);
                const float p1 = fexp2(st[mt][kt][1]);
                const float p2 = fexp2(st[mt][kt][2]);
                const float p3 = fexp2(st[mt][kt][3]);
                uint2 pu = { pk2(p0, p1), pk2(p2, p3) };
                bf16x4s pbv = *reinterpret_cast<bf16x4s*>(&pu);
                const int kp = kt >> 1, hh = kt & 1;
                #pragma unroll
                for (int dt = 0; dt < 4; ++dt) {
                    uint2 vh = hh ? make_uint2(vraw[dt][kp].z, vraw[dt][kp].w)
                                  : make_uint2(vraw[dt][kp].x, vraw[dt][kp].y);
                    bf16x4s va = *reinterpret_cast<bf16x4s*>(&vh);
                    o[mt][dt] = __builtin_amdgcn_mfma_f32_16x16x16bf16_1k(va, pbv, o[mt][dt], 0, 0, 0);
                }
                lsum[mt] = __builtin_amdgcn_mfma_f32_16x16x16bf16_1k(ones4, pbv, lsum[mt], 0, 0, 0);
            }
    }

    // ---- epilogue: l partials + 8-wave 2-buffer O merge (unnormalized) ----
    if (quad == 0) {
        #pragma unroll
        for (int mt = 0; mt < 4; ++mt)
            lbuf[w * 64 + mt * 16 + m16] = lsum[mt][0];
    }
    if (w < 2) {
        float* dst = Ob[w];
        #pragma unroll
        for (int mt = 0; mt < 4; ++mt)
            #pragma unroll
            for (int dt = 0; dt < 4; ++dt)
                *(f32x4*)&dst[(mt * 16 + m16) * 66 + dt * 16 + quad * 4] = o[mt][dt];
    }
    __syncthreads();
    #pragma unroll
    for (int ph = 1; ph < 4; ++ph) {
        if ((w >> 1) == ph) {
            float* dst = Ob[w & 1];
            #pragma unroll
            for (int mt = 0; mt < 4; ++mt)
                #pragma unroll
                for (int dt = 0; dt < 4; ++dt) {
                    float* p = &dst[(mt * 16 + m16) * 66 + dt * 16 + quad * 4];
                    f32x4 cur = *(f32x4*)p;
                    cur += o[mt][dt];
                    *(f32x4*)p = cur;
                }
        }
        __syncthreads();
    }
    // Final: combine the two buffers, store unnormalized; store l partials
    {
        float* Og = Op + (size_t)kh * (2048 * 512);
        const int row = t >> 3;             // 0..63
        const int d0  = (t & 7) << 3;       // 8 floats per thread
        float* op = Og + ((size_t)(b * NQ + qt * 64 + row)) * 512 + h * 64 + d0;
        #pragma unroll
        for (int j = 0; j < 2; ++j) {
            const int c = row * 66 + d0 + j * 4;
            float4 r;
            r.x = Ob[0][c + 0] + Ob[1][c + 0];
            r.y = Ob[0][c + 1] + Ob[1][c + 1];
            r.z = Ob[0][c + 2] + Ob[1][c + 2];
            r.w = Ob[0][c + 3] + Ob[1][c + 3];
            *(float4*)(op + j * 4) = r;
        }
        if (t < 64) {
            float l = 0.f;
            #pragma unroll
            for (int wi = 0; wi < 8; ++wi) l += lbuf[wi * 64 + t];
            Lp[(size_t)kh * (32 * NQ) + bh * NQ + qt * 64 + t] = l;
        }
    }
}

// ---------------------------------------------------------------------------
extern "C" void kernel_launch(void* const* d_in, const int* in_sizes, int n_in,
                              void* d_out, int out_size, void* d_ws, size_t ws_size,
                              hipStream_t stream) {
    (void)in_sizes; (void)n_in; (void)out_size; (void)ws_size;

    const float* x   = (const float*)d_in[0];   // [4, 512, 512]
    const float* ctx = (const float*)d_in[1];   // [4, 8192, 256]
    const float* Wq  = (const float*)d_in[2];   // [512, 512]
    const float* Wkv = (const float*)d_in[3];   // [256, 1024]
    const float* Wo  = (const float*)d_in[4];   // [512, 512]
    const float* bo  = (const float*)d_in[5];   // [512]
    float* out = (float*)d_out;                 // [4, 512, 512]

    float* ws    = (float*)d_ws;
    float* q     = ws;                                       // 4 MB fp32
    float* attno = q + (size_t)2048 * 512;                   // 2 x 4 MB fp32 (kh partials)
    float* lws   = attno + (size_t)2 * 2048 * 512;           // 2 x 64 KB fp32
    short* Kf    = (short*)(lws + (size_t)2 * 32 * NQ);      // 33.5 MB bf16 (fragment order)
    short* Vf    = Kf + (size_t)NB * NH * NM * DH;           // 33.5 MB bf16 (fragment order)
    short* Wqf   = Vf + (size_t)NB * NH * NM * DH;           // 512 KB
    short* Wof   = Wqf + (size_t)512 * 512;                  // 512 KB
    short* Wkvf  = Wof + (size_t)512 * 512;                  // 512 KB

    // weights -> bf16 fragment order
    prep_weights<<<dim3(384), dim3(256), 0, stream>>>(Wq, Wo, Wkv, Wqf, Wof, Wkvf);

    // q = x@Wq (512 blocks) + kv = ctx@Wkv (2048 blocks) in one launch
    gemm_kvq<<<dim3(2560), dim3(256), 0, stream>>>(x, Wqf, q, ctx, Wkvf, Kf, Vf);

    // flash attention: 32 bh x 8 q-tiles x 2 key-halves = 512 blocks x 512 thr
    attn_mfma<<<dim3(512), dim3(512), 0, stream>>>(q, Kf, Vf, attno, lws);

    // out = merge(attno halves) @ Wo + bo (512 blocks)
    gemm_proj32<<<dim3(512), dim3(256), 0, stream>>>(
        attno, attno + (size_t)2048 * 512, lws, lws + (size_t)32 * NQ,
        Wof, out, bo);
}

// Round 5
// 185.431 us; speedup vs baseline: 2.9599x; 1.0308x over previous
//
#include <hip/hip_runtime.h>
#include <hip/hip_bf16.h>
#include <cstdint>

#define NB 4
#define NQ 512
#define NM 8192
#define NH 8
#define DH 64

typedef short bf16x8s __attribute__((ext_vector_type(8)));
typedef short bf16x4s __attribute__((ext_vector_type(4)));
typedef float f32x4  __attribute__((ext_vector_type(4)));

// fast fp32->bf16 (round-half-up)
static __device__ __forceinline__ short f2bs(float f) {
    unsigned u = __builtin_bit_cast(unsigned, f);
    return (short)(unsigned short)((u + 0x8000u) >> 16);
}
// packed pair via v_perm_b32: lo16 = bf16(a), hi16 = bf16(b)
static __device__ __forceinline__ unsigned pk2(float a, float b) {
    unsigned au = __builtin_bit_cast(unsigned, a) + 0x8000u;
    unsigned bu = __builtin_bit_cast(unsigned, b) + 0x8000u;
    return __builtin_amdgcn_perm(bu, au, 0x07060302u);
}

#if __has_builtin(__builtin_amdgcn_exp2f)
static __device__ __forceinline__ float fexp2(float x) { return __builtin_amdgcn_exp2f(x); }
#else
static __device__ __forceinline__ float fexp2(float x) { return exp2f(x); }
#endif

// ---------------------------------------------------------------------------
// Weight prep: Wq/Wo [512,512], Wkv [256,1024] (fp32 [k][n]) -> bf16 MFMA
// B-fragment order: Wf[(n0*KS + ks)*64 + lane][j] = W[ks*32+quad*8+j][n0*16+m16]
// ---------------------------------------------------------------------------
__global__ __launch_bounds__(256) void prep_weights(
    const float* __restrict__ Wq, const float* __restrict__ Wo,
    const float* __restrict__ Wkv,
    short* __restrict__ Wqf, short* __restrict__ Wof, short* __restrict__ Wkvf)
{
    const int t = threadIdx.x;
    const int w = t >> 6, ln = t & 63;
    const int m16 = ln & 15, quad = ln >> 4;
    int f = blockIdx.x * 4 + w;           // 0..1535
    const float* src; short* dst; int N, KS, n0, ks;
    if (f < 512)       { src = Wq;  dst = Wqf;  N = 512;  KS = 16; n0 = f >> 4; ks = f & 15; }
    else if (f < 1024) { f -= 512;  src = Wo;  dst = Wof;  N = 512;  KS = 16; n0 = f >> 4; ks = f & 15; }
    else               { f -= 1024; src = Wkv; dst = Wkvf; N = 1024; KS = 8;  n0 = f >> 3; ks = f & 7; }
    const float* sp = src + (size_t)(ks * 32 + quad * 8) * N + n0 * 16 + m16;
    float v[8];
    #pragma unroll
    for (int j = 0; j < 8; ++j) v[j] = sp[(size_t)j * N];
    uint4 pkv = { pk2(v[0],v[1]), pk2(v[2],v[3]), pk2(v[4],v[5]), pk2(v[6],v[7]) };
    *(uint4*)(dst + ((size_t)(n0 * KS + ks) * 64 + ln) * 8) = pkv;
}

// ---------------------------------------------------------------------------
// Projection GEMM body: C = A[2048,512] @ W[512,512] (+bias).
// 32x64 tile, BK=64; double-buffered LDS, register prefetch.
// ---------------------------------------------------------------------------
__device__ __forceinline__ void proj32_body(
    const float* __restrict__ A, const short* __restrict__ Wf,
    float* __restrict__ C, const float* __restrict__ bias,
    int tm, int tn, char* smemraw, int t)
{
    short* As = (short*)smemraw;        // 2 x [32][72]

    const int w = t >> 6, ln = t & 63;
    const int m16 = ln & 15, quad = ln >> 4;
    const int wm = w >> 1, wn = w & 1;

    const int ar = t >> 3, ac = (t & 7) << 3;      // A: 32 rows x 64 k

    const float* Ap = A + (size_t)(tm * 32 + ar) * 512 + ac;

    f32x4 acc[2] = {};

    {
        float4 a0 = *(const float4*)(Ap);
        float4 a1 = *(const float4*)(Ap + 4);
        uint4 wa = { pk2(a0.x,a0.y), pk2(a0.z,a0.w), pk2(a1.x,a1.y), pk2(a1.z,a1.w) };
        *(uint4*)&As[ar * 72 + ac] = wa;
    }

    #pragma unroll
    for (int k0 = 0; k0 < 512; k0 += 64) {
        short* Ab = As + ((k0 >> 6) & 1) * 2304;
        __syncthreads();

        bf16x8s bfr[2][2];
        #pragma unroll
        for (int ks = 0; ks < 2; ++ks)
            #pragma unroll
            for (int nt = 0; nt < 2; ++nt)
                bfr[ks][nt] = *(const bf16x8s*)(Wf +
                    ((size_t)((tn * 4 + wn * 2 + nt) * 16 + (k0 >> 5) + ks) * 64 + ln) * 8);

        bf16x8s afr[2];
        #pragma unroll
        for (int ks = 0; ks < 2; ++ks)
            afr[ks] = *(const bf16x8s*)&Ab[(wm * 16 + m16) * 72 + ks * 32 + quad * 8];

        float4 a0n, a1n;
        if (k0 + 64 < 512) {
            a0n = *(const float4*)(Ap + k0 + 64);
            a1n = *(const float4*)(Ap + k0 + 68);
        }

        #pragma unroll
        for (int ks = 0; ks < 2; ++ks)
            #pragma unroll
            for (int nt = 0; nt < 2; ++nt)
                acc[nt] = __builtin_amdgcn_mfma_f32_16x16x32_bf16(afr[ks], bfr[ks][nt], acc[nt], 0, 0, 0);

        if (k0 + 64 < 512) {
            short* Abn = As + ((((k0 >> 6) + 1) & 1)) * 2304;
            uint4 wa = { pk2(a0n.x,a0n.y), pk2(a0n.z,a0n.w), pk2(a1n.x,a1n.y), pk2(a1n.z,a1n.w) };
            *(uint4*)&Abn[ar * 72 + ac] = wa;
        }
    }

    const int row0 = tm * 32 + wm * 16 + quad * 4;
    const int col0 = tn * 64 + wn * 32;
    #pragma unroll
    for (int nt = 0; nt < 2; ++nt) {
        const int col = col0 + nt * 16 + m16;
        const float bb = bias ? bias[col] : 0.f;
        #pragma unroll
        for (int r = 0; r < 4; ++r)
            C[(size_t)(row0 + r) * 512 + col] = acc[nt][r] + bb;
    }
}

// ---------------------------------------------------------------------------
// kv GEMM body: 128x128 tile, BK=32, K=256, 256 threads.
// GEMM loop = known-good round-2 version.
//
// NEW fragment layouts for K=32 PV in attention:
//   Key permutation within each 32-key group: S-tile t (t=0,1), C-row
//   R=quad*4+r  <->  key kk = quad*8 + t*4 + r.  After two S-tiles, each
//   lane's quad holds keys quad*8+{0..7} = exactly the 16x16x32 B-operand.
// K epilogue: Kf[(T*2+ks)*512 + (qd*16 + R)*8 + jd], T = g*2 + t:
//   t = quad&1, R = (di*2 + (quad>>1))*4 + r   (LDS transpose, uint4 stores)
// V epilogue: Vf[((dt*256 + g)*64 + (quad_c*16+m16))*8 + jj]:
//   quad_c = di*2 + (quad>>1), jj = (quad&1)*4 + r  (LDS transpose now
//   required: producer lane != consumer lane under the key permutation)
// ---------------------------------------------------------------------------
__device__ __forceinline__ void kv_body(
    const float* __restrict__ A, const short* __restrict__ Wkvf,
    short* __restrict__ Kf, short* __restrict__ Vf,
    int kvid, char* smemraw)
{
    short* As = (short*)smemraw;        // 2 x [128][40]

    const int t  = threadIdx.x;
    // temporal+XCD swizzle: 8 n-tiles of one m-tile are 8 consecutive slots
    // on the same XCD
    const int tm = ((kvid >> 6) << 3) | (kvid & 7);
    const int tn = (kvid >> 3) & 7;
    const int w  = t >> 6, ln = t & 63;
    const int m16 = ln & 15, quad = ln >> 4;
    const int wm = w & 1, wn = w >> 1;

    const int ar = t >> 3;
    const int ac = (t & 7) << 2;

    const float* Abase = A + (size_t)(tm * 128 + ar) * 256 + ac;

    f32x4 acc[4][4] = {};

    // prologue: stage k0=0 into buffer 0
    {
        float4 av[4];
        #pragma unroll
        for (int p = 0; p < 4; ++p)
            av[p] = *(const float4*)(Abase + (size_t)p * 32 * 256);
        #pragma unroll
        for (int p = 0; p < 4; ++p) {
            uint2 wv = { pk2(av[p].x, av[p].y), pk2(av[p].z, av[p].w) };
            *(uint2*)&As[(p * 32 + ar) * 40 + ac] = wv;
        }
    }

    #pragma unroll
    for (int k0 = 0; k0 < 256; k0 += 32) {
        short* Ab = As + ((k0 >> 5) & 1) * 5120;
        __syncthreads();

        bf16x8s bfr[4];
        #pragma unroll
        for (int j = 0; j < 4; ++j)
            bfr[j] = *(const bf16x8s*)(Wkvf +
                ((size_t)((tn * 8 + wn * 4 + j) * 8 + (k0 >> 5)) * 64 + ln) * 8);

        bf16x8s af[4];
        #pragma unroll
        for (int i = 0; i < 4; ++i)
            af[i] = *(const bf16x8s*)&Ab[(wm * 64 + i * 16 + m16) * 40 + quad * 8];

        // prefetch next K-step's A tile into registers
        float4 avn[4];
        if (k0 + 32 < 256) {
            #pragma unroll
            for (int p = 0; p < 4; ++p)
                avn[p] = *(const float4*)(Abase + (size_t)p * 32 * 256 + k0 + 32);
        }

        #pragma unroll
        for (int i = 0; i < 4; ++i)
            #pragma unroll
            for (int j = 0; j < 4; ++j)
                acc[i][j] = __builtin_amdgcn_mfma_f32_16x16x32_bf16(af[i], bfr[j], acc[i][j], 0, 0, 0);

        if (k0 + 32 < 256) {
            short* Abn = As + (((k0 >> 5) + 1) & 1) * 5120;
            #pragma unroll
            for (int p = 0; p < 4; ++p) {
                uint2 wv = { pk2(avn[p].x, avn[p].y), pk2(avn[p].z, avn[p].w) };
                *(uint2*)&Abn[(p * 32 + ar) * 40 + ac] = wv;
            }
        }
    }

    const int col0 = tn * 128 + wn * 64;
    const int row0 = tm * 128 + wm * 64;
    const int b    = row0 >> 13;
    const int mr0  = row0 & (NM - 1);

    if (col0 < 512) {
        // K epilogue: wave-local LDS transpose into permuted-key frag order.
        // acc[i][j][r] = K[key = mr0+i*16+quad*4+r][d = j*16+m16]
        __syncthreads();
        const int h = col0 >> 6;
        short* Kp = Kf + (size_t)(b * NH + h) * (NM * DH);
        short* S  = (short*)smemraw + w * 2048;
        #pragma unroll
        for (int half = 0; half < 2; ++half) {
            const int i0 = half * 2;
            #pragma unroll
            for (int di = 0; di < 2; ++di)
                #pragma unroll
                for (int j = 0; j < 4; ++j) {
                    // t = quad&1 ; ks = j>>1 ; qd = (j&1)*2 + (m16>>3)
                    // R = (di*2 + (quad>>1))*4 + r ; jd = m16&7
                    const int base = ((quad & 1) * 2 + (j >> 1)) * 512
                                   + (((j & 1) * 2 + (m16 >> 3)) * 16
                                      + (di * 2 + (quad >> 1)) * 4) * 8
                                   + (m16 & 7);
                    #pragma unroll
                    for (int r = 0; r < 4; ++r)
                        S[base + r * 8] = f2bs(acc[i0 + di][j][r]);
                }
            // read back lane-contiguous, store coalesced
            const int gf0 = ((mr0 >> 4) + i0) * 2;
            #pragma unroll
            for (int fl = 0; fl < 4; ++fl) {
                uint4 v = *(const uint4*)&S[fl * 512 + ln * 8];
                *(uint4*)(Kp + ((size_t)(gf0 + fl) * 512 + ln * 8)) = v;
            }
        }
    } else {
        // V epilogue: wave-local LDS transpose into 16x16x32 A-operand order.
        // acc[i][j][r] = V[key = mr0+i*16+quad*4+r][d = j*16+m16]
        __syncthreads();
        const int h = (col0 - 512) >> 6;
        short* Vp = Vf + (size_t)(b * NH + h) * (NM * DH);
        short* S  = (short*)smemraw + w * 2048;
        #pragma unroll
        for (int half = 0; half < 2; ++half) {
            const int i0 = half * 2;
            #pragma unroll
            for (int di = 0; di < 2; ++di)
                #pragma unroll
                for (int j = 0; j < 4; ++j) {
                    // consumer lane quad_c = di*2 + (quad>>1), m16 ; jj = (quad&1)*4 + r
                    const int base = j * 512 + (di * 2 + (quad >> 1)) * 128
                                   + m16 * 8 + (quad & 1) * 4;
                    #pragma unroll
                    for (int r = 0; r < 4; ++r)
                        S[base + r] = f2bs(acc[i0 + di][j][r]);
                }
            const int g0 = (mr0 >> 5) + half;
            #pragma unroll
            for (int fl = 0; fl < 4; ++fl) {
                uint4 v = *(const uint4*)&S[fl * 512 + ln * 8];
                *(uint4*)(Vp + ((size_t)(fl * 256 + g0) * 64 + ln) * 8) = v;
            }
        }
    }
}

// ---------------------------------------------------------------------------
// Uber kernel: blocks 0..511 do q = x@Wq (proj32), blocks 512..2559 do kv.
// ---------------------------------------------------------------------------
__global__ __launch_bounds__(256) void gemm_kvq(
    const float* __restrict__ x,   const short* __restrict__ Wqf, float* __restrict__ q,
    const float* __restrict__ ctx, const short* __restrict__ Wkvf,
    short* __restrict__ Kf, short* __restrict__ Vf)
{
    __shared__ __align__(16) char smem[20480];
    if (blockIdx.x < 512)
        proj32_body(x, Wqf, q, nullptr, (int)(blockIdx.x >> 3), (int)(blockIdx.x & 7),
                    smem, (int)threadIdx.x);
    else
        kv_body(ctx, Wkvf, Kf, Vf, (int)(blockIdx.x - 512), smem);
}

// out-projection: 512 blocks x 256 threads
__global__ __launch_bounds__(256) void gemm_proj32(
    const float* __restrict__ A, const short* __restrict__ Wf,
    float* __restrict__ C, const float* __restrict__ bias)
{
    __shared__ __align__(16) char smem[32 * 72 * 2 * 2];
    proj32_body(A, Wf, C, bias, (int)(blockIdx.x >> 3), (int)(blockIdx.x & 7),
                smem, (int)threadIdx.x);
}

// ---------------------------------------------------------------------------
// MFMA flash attention, 32-row q-tiles, full keys, 8 waves (512 thr),
// 512 blocks (2 blocks/CU).  K=32 PV via key-permuted fragments:
// S^T tiles t=0,1 of each 32-key group have C-row quad*4+r = key quad*8+t*4+r,
// so the pk2-packed P values form the 16x16x32 B-operand directly (zero
// cross-lane ops, zero extra VALU).  V stored as K=32 A-operand (V^T rows=d).
// PV: 16 x 16x16x32 + 4 lsum per iter/wave (was 32+8 x 16x16x16_1k).
// ---------------------------------------------------------------------------
__global__ __launch_bounds__(512, 4) void attn_mfma(
    const float* __restrict__ Q,    // [2048, 512] fp32
    const short* __restrict__ Kfr,  // fragment-order K (16x16x32 A-op, permuted keys)
    const short* __restrict__ Vfr,  // fragment-order V (16x16x32 A-op, V^T)
    float* __restrict__ Og)         // [2048, 512] fp32
{
    __shared__ __align__(16) float Ob[2][32 * 66];   // 16.9 KB
    __shared__ float lbuf[8 * 32];

    const int bid = blockIdx.x;
    const int xcd = bid & 7, g = bid >> 3;
    const int bh  = xcd * 4 + (g & 3);     // 16 qt-blocks of one bh share bid%8
    const int qt  = g >> 2;                // 0..15 (32-row tiles)
    const int b   = bh >> 3, h = bh & 7;
    const int t   = threadIdx.x;
    const int w   = t >> 6, ln = t & 63;
    const int m16 = ln & 15, quad = ln >> 4;

    const short* Kbase = Kfr + (size_t)bh * (NM * DH);
    const short* Vbase = Vfr + (size_t)bh * (NM * DH);

    // Q scaled by (1/8) * log2(e)  -> scores in log2 domain
    const float qsc = 0.125f * 1.44269504f;
    bf16x8s qf[2][2];
    #pragma unroll
    for (int mt = 0; mt < 2; ++mt) {
        const float* qrow = Q + ((size_t)(b * NQ + qt * 32 + mt * 16 + m16)) * 512 + h * 64;
        #pragma unroll
        for (int ks = 0; ks < 2; ++ks) {
            float4 x0 = *(const float4*)(qrow + ks * 32 + quad * 8);
            float4 x1 = *(const float4*)(qrow + ks * 32 + quad * 8 + 4);
            uint4 pkv = { pk2(x0.x * qsc, x0.y * qsc), pk2(x0.z * qsc, x0.w * qsc),
                          pk2(x1.x * qsc, x1.y * qsc), pk2(x1.z * qsc, x1.w * qsc) };
            qf[mt][ks] = *reinterpret_cast<bf16x8s*>(&pkv);
        }
    }

    bf16x8s ones8;
    #pragma unroll
    for (int j = 0; j < 8; ++j) ones8[j] = (short)0x3F80;

    f32x4 o[2][4] = {};
    f32x4 lsum[2] = {};

    bf16x8s kf[4][2];
    {
        const int kc = w * 64;
        #pragma unroll
        for (int nt = 0; nt < 4; ++nt)
            #pragma unroll
            for (int ks = 0; ks < 2; ++ks)
                kf[nt][ks] = *(const bf16x8s*)(Kbase + ((((kc >> 4) + nt) * 2 + ks) << 9) + ln * 8);
    }

    for (int it = 0; it < 16; ++it) {
        const int kc = it * 512 + w * 64;

        // V frags: K=32 A-operands, one bf16x8 per (dt, group)
        bf16x8s va8[4][2];
        #pragma unroll
        for (int dt = 0; dt < 4; ++dt)
            #pragma unroll
            for (int gg = 0; gg < 2; ++gg)
                va8[dt][gg] = *(const bf16x8s*)(Vbase + ((size_t)(dt * 256 + (kc >> 5) + gg) * 64 + ln) * 8);

        // S^T : 16x16x32, C rows = permuted keys (key quad*8 + t*4 + r)
        f32x4 st[2][4] = {};
        #pragma unroll
        for (int kt = 0; kt < 4; ++kt)
            #pragma unroll
            for (int mt = 0; mt < 2; ++mt) {
                st[mt][kt] = __builtin_amdgcn_mfma_f32_16x16x32_bf16(kf[kt][0], qf[mt][0], st[mt][kt], 0, 0, 0);
                st[mt][kt] = __builtin_amdgcn_mfma_f32_16x16x32_bf16(kf[kt][1], qf[mt][1], st[mt][kt], 0, 0, 0);
            }

        if (it + 1 < 16) {
            const int kn = (it + 1) * 512 + w * 64;
            #pragma unroll
            for (int nt = 0; nt < 4; ++nt)
                #pragma unroll
                for (int ks = 0; ks < 2; ++ks)
                    kf[nt][ks] = *(const bf16x8s*)(Kbase + ((((kn >> 4) + nt) * 2 + ks) << 9) + ln * 8);
        }

        // p = 2^s; the two S-tiles of a group pack into one K=32 B-operand
        #pragma unroll
        for (int mt = 0; mt < 2; ++mt)
            #pragma unroll
            for (int gg = 0; gg < 2; ++gg) {
                const f32x4 s0 = st[mt][2 * gg];
                const f32x4 s1 = st[mt][2 * gg + 1];
                uint4 pu = { pk2(fexp2(s0[0]), fexp2(s0[1])), pk2(fexp2(s0[2]), fexp2(s0[3])),
                             pk2(fexp2(s1[0]), fexp2(s1[1])), pk2(fexp2(s1[2]), fexp2(s1[3])) };
                bf16x8s pbv = *reinterpret_cast<bf16x8s*>(&pu);
                #pragma unroll
                for (int dt = 0; dt < 4; ++dt)
                    o[mt][dt] = __builtin_amdgcn_mfma_f32_16x16x32_bf16(va8[dt][gg], pbv, o[mt][dt], 0, 0, 0);
                lsum[mt] = __builtin_amdgcn_mfma_f32_16x16x32_bf16(ones8, pbv, lsum[mt], 0, 0, 0);
            }
    }

    // ---- epilogue: l partials + 8-wave 2-buffer O merge ----
    if (quad == 0) {
        #pragma unroll
        for (int mt = 0; mt < 2; ++mt)
            lbuf[w * 32 + mt * 16 + m16] = lsum[mt][0];
    }
    // Phase A: waves 0,1 write buffers 0,1
    if (w < 2) {
        float* dst = Ob[w];
        #pragma unroll
        for (int mt = 0; mt < 2; ++mt)
            #pragma unroll
            for (int dt = 0; dt < 4; ++dt)
                *(f32x4*)&dst[(mt * 16 + m16) * 66 + dt * 16 + quad * 4] = o[mt][dt];
    }
    __syncthreads();
    // Phases B..D: waves {2,3}, {4,5}, {6,7} add into buffers 0,1
    #pragma unroll
    for (int ph = 1; ph < 4; ++ph) {
        if ((w >> 1) == ph) {
            float* dst = Ob[w & 1];
            #pragma unroll
            for (int mt = 0; mt < 2; ++mt)
                #pragma unroll
                for (int dt = 0; dt < 4; ++dt) {
                    float* p = &dst[(mt * 16 + m16) * 66 + dt * 16 + quad * 4];
                    f32x4 cur = *(f32x4*)p;
                    cur += o[mt][dt];
                    *(f32x4*)p = cur;
                }
        }
        __syncthreads();
    }
    // Final: combine the two buffers, normalize, store (512 threads)
    {
        const int row = t >> 4;             // 0..31
        const int d0  = (t & 15) << 2;      // 4 floats per thread
        float l = 0.f;
        #pragma unroll
        for (int wi = 0; wi < 8; ++wi) l += lbuf[wi * 32 + row];
        const float inv = 1.0f / l;
        float* op = Og + ((size_t)(b * NQ + qt * 32 + row)) * 512 + h * 64 + d0;
        const int c = row * 66 + d0;
        float4 r;
        r.x = (Ob[0][c + 0] + Ob[1][c + 0]) * inv;
        r.y = (Ob[0][c + 1] + Ob[1][c + 1]) * inv;
        r.z = (Ob[0][c + 2] + Ob[1][c + 2]) * inv;
        r.w = (Ob[0][c + 3] + Ob[1][c + 3]) * inv;
        *(float4*)op = r;
    }
}

// ---------------------------------------------------------------------------
extern "C" void kernel_launch(void* const* d_in, const int* in_sizes, int n_in,
                              void* d_out, int out_size, void* d_ws, size_t ws_size,
                              hipStream_t stream) {
    (void)in_sizes; (void)n_in; (void)out_size; (void)ws_size;

    const float* x   = (const float*)d_in[0];   // [4, 512, 512]
    const float* ctx = (const float*)d_in[1];   // [4, 8192, 256]
    const float* Wq  = (const float*)d_in[2];   // [512, 512]
    const float* Wkv = (const float*)d_in[3];   // [256, 1024]
    const float* Wo  = (const float*)d_in[4];   // [512, 512]
    const float* bo  = (const float*)d_in[5];   // [512]
    float* out = (float*)d_out;                 // [4, 512, 512]

    float* ws    = (float*)d_ws;
    float* q     = ws;                                       // 4 MB fp32
    float* attno = q + (size_t)2048 * 512;                   // 4 MB fp32
    short* Kf    = (short*)(attno + (size_t)2048 * 512);     // 33.5 MB bf16 (fragment order)
    short* Vf    = Kf + (size_t)NB * NH * NM * DH;           // 33.5 MB bf16 (fragment order)
    short* Wqf   = Vf + (size_t)NB * NH * NM * DH;           // 512 KB
    short* Wof   = Wqf + (size_t)512 * 512;                  // 512 KB
    short* Wkvf  = Wof + (size_t)512 * 512;                  // 512 KB

    // weights -> bf16 fragment order
    prep_weights<<<dim3(384), dim3(256), 0, stream>>>(Wq, Wo, Wkv, Wqf, Wof, Wkvf);

    // q = x@Wq (512 blocks) + kv = ctx@Wkv (2048 blocks) in one launch
    gemm_kvq<<<dim3(2560), dim3(256), 0, stream>>>(x, Wqf, q, ctx, Wkvf, Kf, Vf);

    // flash attention: 32 bh x 16 q-tiles = 512 blocks x 512 threads
    attn_mfma<<<dim3(512), dim3(512), 0, stream>>>(q, Kf, Vf, attno);

    // out = attno @ Wo + bo (512 blocks)
    gemm_proj32<<<dim3(512), dim3(256), 0, stream>>>(attno, Wof, out, bo);
}

// Round 6
// 172.357 us; speedup vs baseline: 3.1845x; 1.0759x over previous
//
#include <hip/hip_runtime.h>
#include <hip/hip_bf16.h>
#include <cstdint>

#define NB 4
#define NQ 512
#define NM 8192
#define NH 8
#define DH 64

typedef short bf16x8s __attribute__((ext_vector_type(8)));
typedef short bf16x4s __attribute__((ext_vector_type(4)));
typedef float f32x4  __attribute__((ext_vector_type(4)));

// fast fp32->bf16 (round-half-up)
static __device__ __forceinline__ short f2bs(float f) {
    unsigned u = __builtin_bit_cast(unsigned, f);
    return (short)(unsigned short)((u + 0x8000u) >> 16);
}
// packed pair via v_perm_b32: lo16 = bf16(a), hi16 = bf16(b)
static __device__ __forceinline__ unsigned pk2(float a, float b) {
    unsigned au = __builtin_bit_cast(unsigned, a) + 0x8000u;
    unsigned bu = __builtin_bit_cast(unsigned, b) + 0x8000u;
    return __builtin_amdgcn_perm(bu, au, 0x07060302u);
}

#if __has_builtin(__builtin_amdgcn_exp2f)
static __device__ __forceinline__ float fexp2(float x) { return __builtin_amdgcn_exp2f(x); }
#else
static __device__ __forceinline__ float fexp2(float x) { return exp2f(x); }
#endif

// ---------------------------------------------------------------------------
// Weight prep: Wq/Wo [512,512], Wkv [256,1024] (fp32 [k][n]) -> bf16 MFMA
// B-fragment order: Wf[(n0*KS + ks)*64 + lane][j] = W[ks*32+quad*8+j][n0*16+m16]
// ---------------------------------------------------------------------------
__global__ __launch_bounds__(256) void prep_weights(
    const float* __restrict__ Wq, const float* __restrict__ Wo,
    const float* __restrict__ Wkv,
    short* __restrict__ Wqf, short* __restrict__ Wof, short* __restrict__ Wkvf)
{
    const int t = threadIdx.x;
    const int w = t >> 6, ln = t & 63;
    const int m16 = ln & 15, quad = ln >> 4;
    int f = blockIdx.x * 4 + w;           // 0..1535
    const float* src; short* dst; int N, KS, n0, ks;
    if (f < 512)       { src = Wq;  dst = Wqf;  N = 512;  KS = 16; n0 = f >> 4; ks = f & 15; }
    else if (f < 1024) { f -= 512;  src = Wo;  dst = Wof;  N = 512;  KS = 16; n0 = f >> 4; ks = f & 15; }
    else               { f -= 1024; src = Wkv; dst = Wkvf; N = 1024; KS = 8;  n0 = f >> 3; ks = f & 7; }
    const float* sp = src + (size_t)(ks * 32 + quad * 8) * N + n0 * 16 + m16;
    float v[8];
    #pragma unroll
    for (int j = 0; j < 8; ++j) v[j] = sp[(size_t)j * N];
    uint4 pkv = { pk2(v[0],v[1]), pk2(v[2],v[3]), pk2(v[4],v[5]), pk2(v[6],v[7]) };
    *(uint4*)(dst + ((size_t)(n0 * KS + ks) * 64 + ln) * 8) = pkv;
}

// ---------------------------------------------------------------------------
// Projection GEMM body: C = A[2048,512] @ W[512,512] (+bias).
// 32x64 tile, BK=64; double-buffered LDS, register prefetch.
// ---------------------------------------------------------------------------
__device__ __forceinline__ void proj32_body(
    const float* __restrict__ A, const short* __restrict__ Wf,
    float* __restrict__ C, const float* __restrict__ bias,
    int tm, int tn, char* smemraw, int t)
{
    short* As = (short*)smemraw;        // 2 x [32][72]

    const int w = t >> 6, ln = t & 63;
    const int m16 = ln & 15, quad = ln >> 4;
    const int wm = w >> 1, wn = w & 1;

    const int ar = t >> 3, ac = (t & 7) << 3;      // A: 32 rows x 64 k

    const float* Ap = A + (size_t)(tm * 32 + ar) * 512 + ac;

    f32x4 acc[2] = {};

    {
        float4 a0 = *(const float4*)(Ap);
        float4 a1 = *(const float4*)(Ap + 4);
        uint4 wa = { pk2(a0.x,a0.y), pk2(a0.z,a0.w), pk2(a1.x,a1.y), pk2(a1.z,a1.w) };
        *(uint4*)&As[ar * 72 + ac] = wa;
    }

    #pragma unroll
    for (int k0 = 0; k0 < 512; k0 += 64) {
        short* Ab = As + ((k0 >> 6) & 1) * 2304;
        __syncthreads();

        bf16x8s bfr[2][2];
        #pragma unroll
        for (int ks = 0; ks < 2; ++ks)
            #pragma unroll
            for (int nt = 0; nt < 2; ++nt)
                bfr[ks][nt] = *(const bf16x8s*)(Wf +
                    ((size_t)((tn * 4 + wn * 2 + nt) * 16 + (k0 >> 5) + ks) * 64 + ln) * 8);

        bf16x8s afr[2];
        #pragma unroll
        for (int ks = 0; ks < 2; ++ks)
            afr[ks] = *(const bf16x8s*)&Ab[(wm * 16 + m16) * 72 + ks * 32 + quad * 8];

        float4 a0n, a1n;
        if (k0 + 64 < 512) {
            a0n = *(const float4*)(Ap + k0 + 64);
            a1n = *(const float4*)(Ap + k0 + 68);
        }

        #pragma unroll
        for (int ks = 0; ks < 2; ++ks)
            #pragma unroll
            for (int nt = 0; nt < 2; ++nt)
                acc[nt] = __builtin_amdgcn_mfma_f32_16x16x32_bf16(afr[ks], bfr[ks][nt], acc[nt], 0, 0, 0);

        if (k0 + 64 < 512) {
            short* Abn = As + ((((k0 >> 6) + 1) & 1)) * 2304;
            uint4 wa = { pk2(a0n.x,a0n.y), pk2(a0n.z,a0n.w), pk2(a1n.x,a1n.y), pk2(a1n.z,a1n.w) };
            *(uint4*)&Abn[ar * 72 + ac] = wa;
        }
    }

    const int row0 = tm * 32 + wm * 16 + quad * 4;
    const int col0 = tn * 64 + wn * 32;
    #pragma unroll
    for (int nt = 0; nt < 2; ++nt) {
        const int col = col0 + nt * 16 + m16;
        const float bb = bias ? bias[col] : 0.f;
        #pragma unroll
        for (int r = 0; r < 4; ++r)
            C[(size_t)(row0 + r) * 512 + col] = acc[nt][r] + bb;
    }
}

// ---------------------------------------------------------------------------
// kv GEMM body, LOW-VGPR variant: 128x128 tile, 512 threads (8 waves),
// per-wave 64x32 output (acc = 32 VGPR -> fits the 64-VGPR occupancy tier:
// waves/SIMD halves at VGPR 64/128/256, so <=64 doubles residency vs 72).
// BK=32, K=256, single-buffer LDS, 2 barriers/step, no register prefetch
// (prefetch measured null twice; TLP from 32 waves/CU hides latency).
// Epilogues write the SAME Kf/Vf fragment formats as round-5 (attn unchanged):
//   K: element K[key][d] -> Kf_h[(g*2+t)*1024 + ks*512 + qc*128 + (qp*4+rr)*8 + jd]
//      key = g*32+qp*8+t*4+rr, d = ks*32+qc*8+jd
//   V: element V[key][d] -> Vf_h[(dt*256+g)*512 + (qcv*16+m16v)*8 + jj]
//      key = g*32+qcv*8+jj, d = dt*16+m16v
// ---------------------------------------------------------------------------
__device__ __forceinline__ void kv_body(
    const float* __restrict__ A, const short* __restrict__ Wkvf,
    short* __restrict__ Kf, short* __restrict__ Vf,
    int kvid, char* smemraw)
{
    short* As = (short*)smemraw;        // [128][40] shorts, 10240 B

    const int t  = threadIdx.x;         // 0..511
    // XCD swizzle: 8 n-tiles of one m-tile on consecutive same-XCD slots
    const int tm  = ((kvid >> 6) << 3) | (kvid & 7);   // 0..255
    const int tn0 = (kvid >> 3) & 7;                   // 128-col tile, 0..7
    const int w  = t >> 6, ln = t & 63;
    const int m16 = ln & 15, quad = ln >> 4;
    const int wm = w & 1, wn = w >> 1;                 // wm: row half, wn: 0..3

    const int ar = t >> 2;            // 0..127
    const int ac = (t & 3) << 3;      // 0,8,16,24 floats

    const float* Abase = A + (size_t)(tm * 128 + ar) * 256 + ac;

    f32x4 acc[4][2] = {};

    for (int s = 0; s < 8; ++s) {
        float4 a0 = *(const float4*)(Abase + s * 32);
        float4 a1 = *(const float4*)(Abase + s * 32 + 4);
        __syncthreads();                 // prior step's readers done
        uint4 wa = { pk2(a0.x,a0.y), pk2(a0.z,a0.w), pk2(a1.x,a1.y), pk2(a1.z,a1.w) };
        *(uint4*)&As[ar * 40 + ac] = wa;
        __syncthreads();

        bf16x8s bfr[2];
        #pragma unroll
        for (int j = 0; j < 2; ++j)
            bfr[j] = *(const bf16x8s*)(Wkvf +
                ((size_t)((tn0 * 8 + wn * 2 + j) * 8 + s) * 64 + ln) * 8);

        #pragma unroll
        for (int i = 0; i < 4; ++i) {
            bf16x8s af = *(const bf16x8s*)&As[(wm * 64 + i * 16 + m16) * 40 + quad * 8];
            acc[i][0] = __builtin_amdgcn_mfma_f32_16x16x32_bf16(af, bfr[0], acc[i][0], 0, 0, 0);
            acc[i][1] = __builtin_amdgcn_mfma_f32_16x16x32_bf16(af, bfr[1], acc[i][1], 0, 0, 0);
        }
    }

    const int row0 = tm * 128;
    const int b    = row0 >> 13;
    const int mr0  = row0 & (NM - 1);
    const int g0   = mr0 >> 5;

    __syncthreads();                     // all As reads done; reuse smem
    short* S = (short*)smemraw + w * 1024;   // 2 KB per wave

    if (tn0 < 4) {
        // K: acc[i][j][r] = K[key = mr0+wm*64+i*16+quad*4+r][d = (wn&1)*32+j*16+m16]
        const int h = tn0 * 2 + (wn >> 1);
        short* Kp = Kf + (size_t)(b * NH + h) * (NM * DH);
        const int ksel = wn & 1;
        #pragma unroll
        for (int hf = 0; hf < 2; ++hf) {
            #pragma unroll
            for (int di = 0; di < 2; ++di) {
                const int i = hf * 2 + di;
                #pragma unroll
                for (int j = 0; j < 2; ++j) {
                    // t=quad&1, qc=j*2+(m16>>3), qp=di*2+(quad>>1), jd=m16&7
                    const int base = (quad & 1) * 512 + (j * 2 + (m16 >> 3)) * 128
                                   + ((di * 2 + (quad >> 1)) * 4) * 8 + (m16 & 7);
                    #pragma unroll
                    for (int r = 0; r < 4; ++r)
                        S[base + r * 8] = f2bs(acc[i][j][r]);
                }
            }
            const int g = g0 + wm * 2 + hf;
            #pragma unroll
            for (int fl = 0; fl < 2; ++fl) {
                uint4 v = *(const uint4*)&S[fl * 512 + ln * 8];
                *(uint4*)(Kp + ((size_t)((g * 2 + fl) * 2 + ksel) * 512 + ln * 8)) = v;
            }
        }
    } else {
        // V: acc[i][j][r] = V[key = mr0+wm*64+i*16+quad*4+r][d = (wn&1)*32+j*16+m16]
        const int h = (tn0 - 4) * 2 + (wn >> 1);
        short* Vp = Vf + (size_t)(b * NH + h) * (NM * DH);
        #pragma unroll
        for (int hf = 0; hf < 2; ++hf) {
            #pragma unroll
            for (int di = 0; di < 2; ++di) {
                const int i = hf * 2 + di;
                #pragma unroll
                for (int j = 0; j < 2; ++j) {
                    // qcv=di*2+(quad>>1), jj=(quad&1)*4+r, block=j
                    const int base = j * 512
                                   + ((di * 2 + (quad >> 1)) * 16 + m16) * 8
                                   + (quad & 1) * 4;
                    #pragma unroll
                    for (int r = 0; r < 4; ++r)
                        S[base + r] = f2bs(acc[i][j][r]);
                }
            }
            const int g = g0 + wm * 2 + hf;
            #pragma unroll
            for (int fl = 0; fl < 2; ++fl) {
                uint4 v = *(const uint4*)&S[fl * 512 + ln * 8];
                *(uint4*)(Vp + ((size_t)((((wn & 1) * 2 + fl) * 256 + g) * 64 + ln) * 8)) = v;
            }
        }
    }
}

// ---------------------------------------------------------------------------
// Uber kernel, 512 threads: blocks 0..255 = q-proj (2 x 32x64 units),
// blocks 256..2303 = kv (128x128 tiles, 8 waves).
// __launch_bounds__(512, 4): empirically caps VGPR at 64 -> 8 waves/SIMD tier.
// ---------------------------------------------------------------------------
__global__ __launch_bounds__(512, 4) void gemm_kvq(
    const float* __restrict__ x,   const short* __restrict__ Wqf, float* __restrict__ q,
    const float* __restrict__ ctx, const short* __restrict__ Wkvf,
    short* __restrict__ Kf, short* __restrict__ Vf)
{
    __shared__ __align__(16) char smem[18432];
    if (blockIdx.x < 256) {
        const int u = (int)(blockIdx.x * 2) + (int)(threadIdx.x >> 8);
        proj32_body(x, Wqf, q, nullptr, u >> 3, u & 7,
                    smem + (threadIdx.x >> 8) * 9216, (int)(threadIdx.x & 255));
    } else {
        kv_body(ctx, Wkvf, Kf, Vf, (int)(blockIdx.x - 256), smem);
    }
}

// out-projection: 512 blocks x 256 threads
__global__ __launch_bounds__(256) void gemm_proj32(
    const float* __restrict__ A, const short* __restrict__ Wf,
    float* __restrict__ C, const float* __restrict__ bias)
{
    __shared__ __align__(16) char smem[32 * 72 * 2 * 2];
    proj32_body(A, Wf, C, bias, (int)(blockIdx.x >> 3), (int)(blockIdx.x & 7),
                smem, (int)threadIdx.x);
}

// ---------------------------------------------------------------------------
// MFMA flash attention (unchanged from round 5), 32-row q-tiles, full keys,
// 8 waves (512 thr), 512 blocks.  K=32 PV via key-permuted fragments.
// ---------------------------------------------------------------------------
__global__ __launch_bounds__(512, 4) void attn_mfma(
    const float* __restrict__ Q,    // [2048, 512] fp32
    const short* __restrict__ Kfr,  // fragment-order K (16x16x32 A-op, permuted keys)
    const short* __restrict__ Vfr,  // fragment-order V (16x16x32 A-op, V^T)
    float* __restrict__ Og)         // [2048, 512] fp32
{
    __shared__ __align__(16) float Ob[2][32 * 66];   // 16.9 KB
    __shared__ float lbuf[8 * 32];

    const int bid = blockIdx.x;
    const int xcd = bid & 7, g = bid >> 3;
    const int bh  = xcd * 4 + (g & 3);     // 16 qt-blocks of one bh share bid%8
    const int qt  = g >> 2;                // 0..15 (32-row tiles)
    const int b   = bh >> 3, h = bh & 7;
    const int t   = threadIdx.x;
    const int w   = t >> 6, ln = t & 63;
    const int m16 = ln & 15, quad = ln >> 4;

    const short* Kbase = Kfr + (size_t)bh * (NM * DH);
    const short* Vbase = Vfr + (size_t)bh * (NM * DH);

    // Q scaled by (1/8) * log2(e)  -> scores in log2 domain
    const float qsc = 0.125f * 1.44269504f;
    bf16x8s qf[2][2];
    #pragma unroll
    for (int mt = 0; mt < 2; ++mt) {
        const float* qrow = Q + ((size_t)(b * NQ + qt * 32 + mt * 16 + m16)) * 512 + h * 64;
        #pragma unroll
        for (int ks = 0; ks < 2; ++ks) {
            float4 x0 = *(const float4*)(qrow + ks * 32 + quad * 8);
            float4 x1 = *(const float4*)(qrow + ks * 32 + quad * 8 + 4);
            uint4 pkv = { pk2(x0.x * qsc, x0.y * qsc), pk2(x0.z * qsc, x0.w * qsc),
                          pk2(x1.x * qsc, x1.y * qsc), pk2(x1.z * qsc, x1.w * qsc) };
            qf[mt][ks] = *reinterpret_cast<bf16x8s*>(&pkv);
        }
    }

    bf16x8s ones8;
    #pragma unroll
    for (int j = 0; j < 8; ++j) ones8[j] = (short)0x3F80;

    f32x4 o[2][4] = {};
    f32x4 lsum[2] = {};

    bf16x8s kf[4][2];
    {
        const int kc = w * 64;
        #pragma unroll
        for (int nt = 0; nt < 4; ++nt)
            #pragma unroll
            for (int ks = 0; ks < 2; ++ks)
                kf[nt][ks] = *(const bf16x8s*)(Kbase + ((((kc >> 4) + nt) * 2 + ks) << 9) + ln * 8);
    }

    for (int it = 0; it < 16; ++it) {
        const int kc = it * 512 + w * 64;

        // V frags: K=32 A-operands, one bf16x8 per (dt, group)
        bf16x8s va8[4][2];
        #pragma unroll
        for (int dt = 0; dt < 4; ++dt)
            #pragma unroll
            for (int gg = 0; gg < 2; ++gg)
                va8[dt][gg] = *(const bf16x8s*)(Vbase + ((size_t)(dt * 256 + (kc >> 5) + gg) * 64 + ln) * 8);

        // S^T : 16x16x32, C rows = permuted keys (key quad*8 + t*4 + r)
        f32x4 st[2][4] = {};
        #pragma unroll
        for (int kt = 0; kt < 4; ++kt)
            #pragma unroll
            for (int mt = 0; mt < 2; ++mt) {
                st[mt][kt] = __builtin_amdgcn_mfma_f32_16x16x32_bf16(kf[kt][0], qf[mt][0], st[mt][kt], 0, 0, 0);
                st[mt][kt] = __builtin_amdgcn_mfma_f32_16x16x32_bf16(kf[kt][1], qf[mt][1], st[mt][kt], 0, 0, 0);
            }

        if (it + 1 < 16) {
            const int kn = (it + 1) * 512 + w * 64;
            #pragma unroll
            for (int nt = 0; nt < 4; ++nt)
                #pragma unroll
                for (int ks = 0; ks < 2; ++ks)
                    kf[nt][ks] = *(const bf16x8s*)(Kbase + ((((kn >> 4) + nt) * 2 + ks) << 9) + ln * 8);
        }

        // p = 2^s; the two S-tiles of a group pack into one K=32 B-operand
        #pragma unroll
        for (int mt = 0; mt < 2; ++mt)
            #pragma unroll
            for (int gg = 0; gg < 2; ++gg) {
                const f32x4 s0 = st[mt][2 * gg];
                const f32x4 s1 = st[mt][2 * gg + 1];
                uint4 pu = { pk2(fexp2(s0[0]), fexp2(s0[1])), pk2(fexp2(s0[2]), fexp2(s0[3])),
                             pk2(fexp2(s1[0]), fexp2(s1[1])), pk2(fexp2(s1[2]), fexp2(s1[3])) };
                bf16x8s pbv = *reinterpret_cast<bf16x8s*>(&pu);
                #pragma unroll
                for (int dt = 0; dt < 4; ++dt)
                    o[mt][dt] = __builtin_amdgcn_mfma_f32_16x16x32_bf16(va8[dt][gg], pbv, o[mt][dt], 0, 0, 0);
                lsum[mt] = __builtin_amdgcn_mfma_f32_16x16x32_bf16(ones8, pbv, lsum[mt], 0, 0, 0);
            }
    }

    // ---- epilogue: l partials + 8-wave 2-buffer O merge ----
    if (quad == 0) {
        #pragma unroll
        for (int mt = 0; mt < 2; ++mt)
            lbuf[w * 32 + mt * 16 + m16] = lsum[mt][0];
    }
    // Phase A: waves 0,1 write buffers 0,1
    if (w < 2) {
        float* dst = Ob[w];
        #pragma unroll
        for (int mt = 0; mt < 2; ++mt)
            #pragma unroll
            for (int dt = 0; dt < 4; ++dt)
                *(f32x4*)&dst[(mt * 16 + m16) * 66 + dt * 16 + quad * 4] = o[mt][dt];
    }
    __syncthreads();
    // Phases B..D: waves {2,3}, {4,5}, {6,7} add into buffers 0,1
    #pragma unroll
    for (int ph = 1; ph < 4; ++ph) {
        if ((w >> 1) == ph) {
            float* dst = Ob[w & 1];
            #pragma unroll
            for (int mt = 0; mt < 2; ++mt)
                #pragma unroll
                for (int dt = 0; dt < 4; ++dt) {
                    float* p = &dst[(mt * 16 + m16) * 66 + dt * 16 + quad * 4];
                    f32x4 cur = *(f32x4*)p;
                    cur += o[mt][dt];
                    *(f32x4*)p = cur;
                }
        }
        __syncthreads();
    }
    // Final: combine the two buffers, normalize, store (512 threads)
    {
        const int row = t >> 4;             // 0..31
        const int d0  = (t & 15) << 2;      // 4 floats per thread
        float l = 0.f;
        #pragma unroll
        for (int wi = 0; wi < 8; ++wi) l += lbuf[wi * 32 + row];
        const float inv = 1.0f / l;
        float* op = Og + ((size_t)(b * NQ + qt * 32 + row)) * 512 + h * 64 + d0;
        const int c = row * 66 + d0;
        float4 r;
        r.x = (Ob[0][c + 0] + Ob[1][c + 0]) * inv;
        r.y = (Ob[0][c + 1] + Ob[1][c + 1]) * inv;
        r.z = (Ob[0][c + 2] + Ob[1][c + 2]) * inv;
        r.w = (Ob[0][c + 3] + Ob[1][c + 3]) * inv;
        *(float4*)op = r;
    }
}

// ---------------------------------------------------------------------------
extern "C" void kernel_launch(void* const* d_in, const int* in_sizes, int n_in,
                              void* d_out, int out_size, void* d_ws, size_t ws_size,
                              hipStream_t stream) {
    (void)in_sizes; (void)n_in; (void)out_size; (void)ws_size;

    const float* x   = (const float*)d_in[0];   // [4, 512, 512]
    const float* ctx = (const float*)d_in[1];   // [4, 8192, 256]
    const float* Wq  = (const float*)d_in[2];   // [512, 512]
    const float* Wkv = (const float*)d_in[3];   // [256, 1024]
    const float* Wo  = (const float*)d_in[4];   // [512, 512]
    const float* bo  = (const float*)d_in[5];   // [512]
    float* out = (float*)d_out;                 // [4, 512, 512]

    float* ws    = (float*)d_ws;
    float* q     = ws;                                       // 4 MB fp32
    float* attno = q + (size_t)2048 * 512;                   // 4 MB fp32
    short* Kf    = (short*)(attno + (size_t)2048 * 512);     // 33.5 MB bf16 (fragment order)
    short* Vf    = Kf + (size_t)NB * NH * NM * DH;           // 33.5 MB bf16 (fragment order)
    short* Wqf   = Vf + (size_t)NB * NH * NM * DH;           // 512 KB
    short* Wof   = Wqf + (size_t)512 * 512;                  // 512 KB
    short* Wkvf  = Wof + (size_t)512 * 512;                  // 512 KB

    // weights -> bf16 fragment order
    prep_weights<<<dim3(384), dim3(256), 0, stream>>>(Wq, Wo, Wkv, Wqf, Wof, Wkvf);

    // q = x@Wq (256 blocks x 2 units) + kv = ctx@Wkv (2048 blocks), 512 thr
    gemm_kvq<<<dim3(2304), dim3(512), 0, stream>>>(x, Wqf, q, ctx, Wkvf, Kf, Vf);

    // flash attention: 32 bh x 16 q-tiles = 512 blocks x 512 threads
    attn_mfma<<<dim3(512), dim3(512), 0, stream>>>(q, Kf, Vf, attno);

    // out = attno @ Wo + bo (512 blocks)
    gemm_proj32<<<dim3(512), dim3(256), 0, stream>>>(attno, Wof, out, bo);
}